// Round 12
// baseline (60.067 us; speedup 1.0000x reference)
//
#include <hip/hip_runtime.h>
#include <math.h>

#define T_SEQ 2048
#define DMODEL 256
#define C_HEAD 64
#define NH 4
#define NWIN 16
#define B_SZ 4

typedef __attribute__((ext_vector_type(8))) short bf16x8;
typedef __attribute__((ext_vector_type(8))) unsigned short ushort8;
typedef __attribute__((ext_vector_type(4))) float f32x4;

static __device__ __forceinline__ unsigned short f2bf(float f) {
    union { float f; unsigned int u; } v; v.f = f;
    unsigned int r = v.u + 0x7FFFu + ((v.u >> 16) & 1u);
    return (unsigned short)(r >> 16);
}

// packed offset for a (col,k) element in a K=256 fragment-major region
static __device__ __forceinline__ long pk256(int col, int k) {
    return ((long)(col >> 4) * 8 + (k >> 5)) * 512 + ((k >> 3) & 3) * 128 + (col & 15) * 8 + (k & 7);
}

// ---------------- conv_w --------------------------------------------------
// blocks 0..47:    region1 pack (K=256): cols [WQ(256) WK(64) WV(64)]
// blocks 48..111:  M = [Wout[:,:64]@Wg0 | Wout[:,64:]@Wg1]  (256x256, K=256
//                  fragment-major at elem offset 98304)
// block 112:       beff[d] = bout[d] + Wout[d,:64]@bg0 + Wout[d,64:]@bg1
// blocks 113..176: rope table rtab[t][k] = (cos,sin)(t * 10000^(-k/8))
__global__ __launch_bounds__(256) void conv_w_kernel(
    const float* __restrict__ WQ, const float* __restrict__ WK,
    const float* __restrict__ WV, const float* __restrict__ Wg0,
    const float* __restrict__ Wg1, const float* __restrict__ Wout,
    const float* __restrict__ bg0, const float* __restrict__ bg1,
    const float* __restrict__ bout,
    unsigned short* __restrict__ dst, float* __restrict__ beff,
    float2* __restrict__ rtab) {
    const int tid = threadIdx.x;
    const int blk = blockIdx.x;
    if (blk < 48) {                                     // region1 pack
        const int i = blk * 256 + tid;                  // vec8 index
        const long e = (long)i * 8;
        const int col = (int)(e >> 8), k = (int)(e & 255);
        const float* s; long off;
        if      (col < 256) { s = WQ; off = (long)col * 256 + k; }
        else if (col < 320) { s = WK; off = (long)(col - 256) * 256 + k; }
        else                { s = WV; off = (long)(col - 320) * 256 + k; }
        const float4* s4 = (const float4*)(s + off);
        float4 a = s4[0], b = s4[1];
        ushort8 o;
        o[0] = f2bf(a.x); o[1] = f2bf(a.y); o[2] = f2bf(a.z); o[3] = f2bf(a.w);
        o[4] = f2bf(b.x); o[5] = f2bf(b.y); o[6] = f2bf(b.z); o[7] = f2bf(b.w);
        *(ushort8*)(dst + pk256(col, k)) = o;           // k%8==0 so contiguous
    } else if (blk < 112) {                             // M combine
        const int idx = (blk - 48) * 1024 + tid * 4;
        const int d = idx >> 8;
        const int c0 = idx & 255;
        const float* wrow = Wout + (long)d * 128;
        float m[4] = {0.f, 0.f, 0.f, 0.f};
        for (int j = 0; j < 64; ++j) {
            float w0 = wrow[j], w1 = wrow[64 + j];
            #pragma unroll
            for (int u = 0; u < 4; ++u) {
                int c = c0 + u;
                m[u] += (c < 128) ? w0 * Wg0[j * 128 + c]
                                  : w1 * Wg1[j * 128 + (c - 128)];
            }
        }
        unsigned short* Mpk = dst + 98304;
        #pragma unroll
        for (int u = 0; u < 4; ++u)
            Mpk[pk256(d, c0 + u)] = f2bf(m[u]);
    } else if (blk == 112) {                            // beff
        const int d = tid;
        const float* wrow = Wout + (long)d * 128;
        float s = bout[d];
        for (int j = 0; j < 64; ++j)
            s += wrow[j] * bg0[j] + wrow[64 + j] * bg1[j];
        beff[d] = s;
    } else {                                            // rope table
        const int idx = (blk - 113) * 256 + tid;        // 0..16383
        const int t = idx >> 3, k = idx & 7;
        const float theta = powf(10000.0f, -0.125f * (float)k);
        const float fr = (float)t * theta;
        rtab[idx] = make_float2(cosf(fr), sinf(fr));
    }
}

// ---------------- fused kernel: BM=16, 4 waves, 4 blocks/CU --------------
// grid = B*(T/16) = 512 blocks, 256 thr. Wave h:
//   QKV: Q head h (16 toks) + {K,V} half (sel=h>>1, mfh=h&1) interleaved.
//   Attention: head h (S^T = mfma(K,Q), softmax, P relayout, PV via V^T).
//   Out: single combined projection out = O @ M^T + beff (K=256).
__global__ __launch_bounds__(256) void fused_kernel(
    const float* __restrict__ H, const unsigned short* __restrict__ Wallb,
    const float* __restrict__ wq, const float* __restrict__ wk,
    const float* __restrict__ wv, const float2* __restrict__ rtab,
    const float* __restrict__ beff, float* __restrict__ out)
{
    __shared__ __align__(16) char smem[37888];
    char* lds_a = smem;            // [32][512B] H staging (16KB)  [phase A]
    char* o_lds = smem;            // [16][512B] O tile (8KB)      [reuse]
    char* q_lds = smem + 16384;    // 4 heads x [16][128B] (8KB)
    char* k_lds = smem + 24576;    // [32][128B] (4KB)
    char* v_t   = smem + 28672;    // V^T [64 ch][80B stride] (5KB)
    char* p_att = smem + 33792;    // 4 waves x 1KB

    const int tid = threadIdx.x;
    const int blk = blockIdx.x;
    const int b  = blk >> 7;
    const int t0 = (blk & 127) << 4;

    const unsigned short* Mpk = Wallb + 98304;

    // ---- stage H rows [t0-16, t0+16) (clamped), f32 -> bf16, swizzled ----
    for (int idx = tid; idx < 1024; idx += 256) {
        int row = idx >> 5, ch = idx & 31;
        int t = t0 - 16 + row; if (t < 0) t = 0;       // masked later
        const float4* s4 = (const float4*)(H + ((size_t)b * T_SEQ + t) * DMODEL + ch * 8);
        float4 a = s4[0], c = s4[1];
        ushort8 o;
        o[0] = f2bf(a.x); o[1] = f2bf(a.y); o[2] = f2bf(a.z); o[3] = f2bf(a.w);
        o[4] = f2bf(c.x); o[5] = f2bf(c.y); o[6] = f2bf(c.z); o[7] = f2bf(c.w);
        int byte = row * 512 + ch * 16;
        byte ^= (row & 7) << 4;
        *(ushort8*)(lds_a + byte) = o;
    }
    __syncthreads();

    const int h  = tid >> 6;       // wave = head
    const int l  = tid & 63;
    const int g  = l >> 4;
    const int li = l & 15;
    const int lane16 = l * 8;      // packed-W per-lane elem offset (16B/lane)

    const int sel = h >> 1;        // 0 = K, 1 = V
    const int mfh = h & 1;         // halo row half

    // ---- QKV: Q head h + K/V half, interleaved ---------------------------
    f32x4 accq[4] = {};
    f32x4 acckv[4] = {};
    #pragma unroll
    for (int ks = 0; ks < 8; ++ks) {
        const int rowq = 16 + li;
        int bq = rowq * 512 + (ks * 32 + g * 8) * 2;
        bq ^= (rowq & 7) << 4;
        bf16x8 aq = *(const bf16x8*)(lds_a + bq);
        const int rowk = mfh * 16 + li;
        int bk = rowk * 512 + (ks * 32 + g * 8) * 2;
        bk ^= (rowk & 7) << 4;
        bf16x8 akv = *(const bf16x8*)(lds_a + bk);
        #pragma unroll
        for (int nf = 0; nf < 4; ++nf) {
            bf16x8 bqf = *(const bf16x8*)(Wallb + (size_t)((h * 4 + nf) * 8 + ks) * 512 + lane16);
            accq[nf] = __builtin_amdgcn_mfma_f32_16x16x32_bf16(aq, bqf, accq[nf], 0, 0, 0);
            bf16x8 bkf = *(const bf16x8*)(Wallb + (size_t)((16 + sel * 4 + nf) * 8 + ks) * 512 + lane16);
            acckv[nf] = __builtin_amdgcn_mfma_f32_16x16x32_bf16(akv, bkf, acckv[nf], 0, 0, 0);
        }
    }

    // ---- Q epilogue: rmsnorm + rope -> q_lds[h] --------------------------
    {
        float gw[4];
        #pragma unroll
        for (int nf = 0; nf < 4; ++nf) gw[nf] = wq[h * 64 + nf * 16 + li];
        #pragma unroll
        for (int r = 0; r < 4; ++r) {
            float x0 = accq[0][r], x1 = accq[1][r];
            float x2 = accq[2][r], x3 = accq[3][r];
            float ss = x0 * x0 + x1 * x1 + x2 * x2 + x3 * x3;
            ss += __shfl_xor(ss, 1);
            ss += __shfl_xor(ss, 2);
            ss += __shfl_xor(ss, 4);
            ss += __shfl_xor(ss, 8);
            const float rinv = rsqrtf(ss * (1.0f / 64.0f) + 1e-8f);
            const int tok = g * 4 + r;
            const int t = t0 + tok;
            float v0 = x0 * rinv * gw[0];
            float v1 = x1 * rinv * gw[1];
            float v2 = x2 * rinv * gw[2];
            float v3 = x3 * rinv * gw[3];
            float2 cs = rtab[t * 8 + (li >> 1)];
            float px = __shfl_xor(v3, 1);
            v3 = ((li & 1) == 0) ? (v3 * cs.x - px * cs.y) : (px * cs.y + v3 * cs.x);
            char* qb = q_lds + h * 2048;
            const int sw = (tok & 7) << 4;
            *(unsigned short*)(qb + ((tok * 128 + (0 * 16 + li) * 2) ^ sw)) = f2bf(v0);
            *(unsigned short*)(qb + ((tok * 128 + (1 * 16 + li) * 2) ^ sw)) = f2bf(v1);
            *(unsigned short*)(qb + ((tok * 128 + (2 * 16 + li) * 2) ^ sw)) = f2bf(v2);
            *(unsigned short*)(qb + ((tok * 128 + (3 * 16 + li) * 2) ^ sw)) = f2bf(v3);
        }
    }

    // ---- K/V epilogue: rmsnorm + rope -> k_lds / v_t ---------------------
    {
        float gw[4];
        #pragma unroll
        for (int nf = 0; nf < 4; ++nf)
            gw[nf] = (sel == 0) ? wk[nf * 16 + li] : wv[nf * 16 + li];
        #pragma unroll
        for (int r = 0; r < 4; ++r) {
            float x0 = acckv[0][r], x1 = acckv[1][r];
            float x2 = acckv[2][r], x3 = acckv[3][r];
            float ss = x0 * x0 + x1 * x1 + x2 * x2 + x3 * x3;
            ss += __shfl_xor(ss, 1);
            ss += __shfl_xor(ss, 2);
            ss += __shfl_xor(ss, 4);
            ss += __shfl_xor(ss, 8);
            const float rinv = rsqrtf(ss * (1.0f / 64.0f) + 1e-8f);
            const int row = mfh * 16 + g * 4 + r;      // halo row 0..31
            int tk = t0 - 16 + row; if (tk < 0) tk = 0;
            float v0 = x0 * rinv * gw[0];
            float v1 = x1 * rinv * gw[1];
            float v2 = x2 * rinv * gw[2];
            float v3 = x3 * rinv * gw[3];
            float2 cs = rtab[tk * 8 + (li >> 1)];
            float px = __shfl_xor(v3, 1);
            v3 = ((li & 1) == 0) ? (v3 * cs.x - px * cs.y) : (px * cs.y + v3 * cs.x);
            if (sel == 0) {
                const int sw = (row & 7) << 4;
                *(unsigned short*)(k_lds + ((row * 128 + (0 * 16 + li) * 2) ^ sw)) = f2bf(v0);
                *(unsigned short*)(k_lds + ((row * 128 + (1 * 16 + li) * 2) ^ sw)) = f2bf(v1);
                *(unsigned short*)(k_lds + ((row * 128 + (2 * 16 + li) * 2) ^ sw)) = f2bf(v2);
                *(unsigned short*)(k_lds + ((row * 128 + (3 * 16 + li) * 2) ^ sw)) = f2bf(v3);
            } else {
                *(unsigned short*)(v_t + (0 * 16 + li) * 80 + row * 2) = f2bf(v0);
                *(unsigned short*)(v_t + (1 * 16 + li) * 80 + row * 2) = f2bf(v1);
                *(unsigned short*)(v_t + (2 * 16 + li) * 80 + row * 2) = f2bf(v2);
                *(unsigned short*)(v_t + (3 * 16 + li) * 80 + row * 2) = f2bf(v3);
            }
        }
    }
    __syncthreads();

    // ---- attention: head h -----------------------------------------------
    {
        bf16x8 qf0, qf1;
        {
            const char* qb = q_lds + h * 2048;
            const int sw = (li & 7) << 4;
            qf0 = *(const bf16x8*)(qb + ((li * 128 + g * 16) ^ sw));
            qf1 = *(const bf16x8*)(qb + ((li * 128 + 64 + g * 16) ^ sw));
        }
        f32x4 st[2];
        #pragma unroll
        for (int tile = 0; tile < 2; ++tile) {
            const int row = tile * 16 + li;
            const int sw = (row & 7) << 4;
            bf16x8 kf0 = *(const bf16x8*)(k_lds + ((row * 128 + g * 16) ^ sw));
            bf16x8 kf1 = *(const bf16x8*)(k_lds + ((row * 128 + 64 + g * 16) ^ sw));
            f32x4 acc = {};
            acc = __builtin_amdgcn_mfma_f32_16x16x32_bf16(kf0, qf0, acc, 0, 0, 0);
            acc = __builtin_amdgcn_mfma_f32_16x16x32_bf16(kf1, qf1, acc, 0, 0, 0);
            st[tile] = acc;
        }

        float p[8];
        float mx = -1e30f;
        #pragma unroll
        for (int tile = 0; tile < 2; ++tile) {
            #pragma unroll
            for (int r = 0; r < 4; ++r) {
                int krel = tile * 16 - 16 + g * 4 + r;
                int dd = li - krel;
                bool ok = ((unsigned)dd < 16u) && (t0 + krel >= 0);
                float v = ok ? st[tile][r] * 0.125f : -1e30f;
                p[tile * 4 + r] = v;
                mx = fmaxf(mx, v);
            }
        }
        mx = fmaxf(mx, __shfl_xor(mx, 16));
        mx = fmaxf(mx, __shfl_xor(mx, 32));
        float sum = 0.f;
        #pragma unroll
        for (int i = 0; i < 8; ++i) { p[i] = __expf(p[i] - mx); sum += p[i]; }
        sum += __shfl_xor(sum, 16);
        sum += __shfl_xor(sum, 32);
        const float inv = 1.0f / sum;

        // P -> wave-local LDS relayout to K=32 A-fragment
        bf16x8 paf;
        {
            char* pbase = p_att + h * 1024;
            uint2 w0, w1;
            w0.x = (unsigned)f2bf(p[0] * inv) | ((unsigned)f2bf(p[1] * inv) << 16);
            w0.y = (unsigned)f2bf(p[2] * inv) | ((unsigned)f2bf(p[3] * inv) << 16);
            w1.x = (unsigned)f2bf(p[4] * inv) | ((unsigned)f2bf(p[5] * inv) << 16);
            w1.y = (unsigned)f2bf(p[6] * inv) | ((unsigned)f2bf(p[7] * inv) << 16);
            const int sw = (li & 3) << 4;
            *(uint2*)(pbase + ((li * 64 + 0 * 32 + g * 8) ^ sw)) = w0;
            *(uint2*)(pbase + ((li * 64 + 1 * 32 + g * 8) ^ sw)) = w1;
            asm volatile("s_waitcnt lgkmcnt(0)" ::: "memory");
            paf = *(const bf16x8*)(pbase + ((li * 64 + g * 16) ^ sw));
        }

        // PV via V^T: single b128 B-frag per ctile
        f32x4 o[4] = {};
        #pragma unroll
        for (int ctile = 0; ctile < 4; ++ctile) {
            bf16x8 vf = *(const bf16x8*)(v_t + (ctile * 16 + li) * 80 + g * 16);
            o[ctile] = __builtin_amdgcn_mfma_f32_16x16x32_bf16(paf, vf, o[ctile], 0, 0, 0);
        }

        // inverse rope on chans 48..63 (ctile 3); write O to swizzled LDS
        #pragma unroll
        for (int r = 0; r < 4; ++r) {
            const int row = g * 4 + r;
            const int t = t0 + row;
            float o3 = o[3][r];
            float po = __shfl_xor(o3, 1);
            float2 cs = rtab[t * 8 + (li >> 1)];
            o3 = ((li & 1) == 0) ? (o3 * cs.x + po * cs.y) : (-po * cs.y + o3 * cs.x);
            #pragma unroll
            for (int ctile = 0; ctile < 4; ++ctile) {
                const int col = h * 64 + ctile * 16 + li;
                int byte = row * 512 + col * 2;
                byte ^= (row & 7) << 4;
                float val = (ctile == 3) ? o3 : o[ctile][r];
                *(unsigned short*)(o_lds + byte) = f2bf(val);
            }
        }
    }
    __syncthreads();

    // ---- combined out projection: out = O @ M^T + beff (K=256) -----------
    {
        f32x4 acco[4] = {};
        #pragma unroll
        for (int ks = 0; ks < 8; ++ks) {
            int byte = li * 512 + (ks * 32 + g * 8) * 2;
            byte ^= (li & 7) << 4;
            bf16x8 a = *(const bf16x8*)(o_lds + byte);
            #pragma unroll
            for (int nf = 0; nf < 4; ++nf) {
                const int colblk = h * 4 + nf;
                bf16x8 bfr = *(const bf16x8*)(Mpk + (size_t)(colblk * 8 + ks) * 512 + lane16);
                acco[nf] = __builtin_amdgcn_mfma_f32_16x16x32_bf16(a, bfr, acco[nf], 0, 0, 0);
            }
        }
        #pragma unroll
        for (int nf = 0; nf < 4; ++nf) {
            const int col = h * 64 + nf * 16 + li;
            const float bb = beff[col];
            #pragma unroll
            for (int r = 0; r < 4; ++r) {
                const int row = g * 4 + r;
                out[(size_t)(b * T_SEQ + t0 + row) * DMODEL + col] = acco[nf][r] + bb;
            }
        }
    }
}

extern "C" void kernel_launch(void* const* d_in, const int* in_sizes, int n_in,
                              void* d_out, int out_size, void* d_ws, size_t ws_size,
                              hipStream_t stream) {
    const float* H    = (const float*)d_in[0];
    const float* WQ   = (const float*)d_in[1];
    const float* WK   = (const float*)d_in[2];
    const float* WV   = (const float*)d_in[3];
    const float* wq   = (const float*)d_in[4];
    const float* wk   = (const float*)d_in[5];
    const float* wv   = (const float*)d_in[6];
    const float* Wg0  = (const float*)d_in[7];
    const float* bg0  = (const float*)d_in[8];
    const float* Wg1  = (const float*)d_in[9];
    const float* bg1  = (const float*)d_in[10];
    const float* Wout = (const float*)d_in[11];
    const float* bout = (const float*)d_in[12];
    float* out = (float*)d_out;

    char* ws = (char*)d_ws;
    unsigned short* Wallb = (unsigned short*)ws;          // 327,680 B (region1 + M)
    float* beff = (float*)(ws + 327680);                  //   1,024 B
    float2* rtab = (float2*)(ws + 331776);                // 131,072 B

    conv_w_kernel<<<177, 256, 0, stream>>>(WQ, WK, WV, Wg0, Wg1, Wout,
                                           bg0, bg1, bout, Wallb, beff, rtab);
    fused_kernel<<<B_SZ * T_SEQ / 16, 256, 0, stream>>>(H, Wallb, wq, wk, wv, rtab,
                                                        beff, out);
}

// Round 13
// 25.185 us; speedup vs baseline: 2.3851x; 2.3851x over previous
//
#include <hip/hip_runtime.h>
#include <math.h>

#define T_SEQ 2048
#define DMODEL 256
#define C_HEAD 64
#define NH 4
#define NWIN 16
#define B_SZ 4

typedef __attribute__((ext_vector_type(8))) short bf16x8;
typedef __attribute__((ext_vector_type(8))) unsigned short ushort8;
typedef __attribute__((ext_vector_type(4))) float f32x4;

static __device__ __forceinline__ unsigned short f2bf(float f) {
    union { float f; unsigned int u; } v; v.f = f;
    unsigned int r = v.u + 0x7FFFu + ((v.u >> 16) & 1u);
    return (unsigned short)(r >> 16);
}

// packed offset for a (col,k) element in a K=256 fragment-major region
static __device__ __forceinline__ long pk256(int col, int k) {
    return ((long)(col >> 4) * 8 + (k >> 5)) * 512 + ((k >> 3) & 3) * 128 + (col & 15) * 8 + (k & 7);
}

// ---------------- conv_w --------------------------------------------------
// blocks 0..47:    region1 pack (K=256): cols [WQ(256) WK(64) WV(64)]
// blocks 48..303:  M[d,:] for d = blk-48. M = [Wout[:,:64]@Wg0 | Wout[:,64:]@Wg1]
//                  (256x256), fragment-major at elem offset 98304.
// block 304:       beff[d] = bout[d] + Wout[d,:64]@bg0 + Wout[d,64:]@bg1
// blocks 305..368: rope table rtab[t][k] = (cos,sin)(t * 10000^(-k/8))
__global__ __launch_bounds__(256) void conv_w_kernel(
    const float* __restrict__ WQ, const float* __restrict__ WK,
    const float* __restrict__ WV, const float* __restrict__ Wg0,
    const float* __restrict__ Wg1, const float* __restrict__ Wout,
    const float* __restrict__ bg0, const float* __restrict__ bg1,
    const float* __restrict__ bout,
    unsigned short* __restrict__ dst, float* __restrict__ beff,
    float2* __restrict__ rtab) {
    const int tid = threadIdx.x;
    const int blk = blockIdx.x;
    if (blk < 48) {                                     // region1 pack
        const int i = blk * 256 + tid;                  // vec8 index
        const long e = (long)i * 8;
        const int col = (int)(e >> 8), k = (int)(e & 255);
        const float* s; long off;
        if      (col < 256) { s = WQ; off = (long)col * 256 + k; }
        else if (col < 320) { s = WK; off = (long)(col - 256) * 256 + k; }
        else                { s = WV; off = (long)(col - 320) * 256 + k; }
        const float4* s4 = (const float4*)(s + off);
        float4 a = s4[0], b = s4[1];
        ushort8 o;
        o[0] = f2bf(a.x); o[1] = f2bf(a.y); o[2] = f2bf(a.z); o[3] = f2bf(a.w);
        o[4] = f2bf(b.x); o[5] = f2bf(b.y); o[6] = f2bf(b.z); o[7] = f2bf(b.w);
        *(ushort8*)(dst + pk256(col, k)) = o;           // k%8==0 so contiguous
    } else if (blk < 304) {                             // M row d = blk-48
        const int d = blk - 48;
        const int c = tid;                              // output col 0..255
        const float* wrow = Wout + (long)d * 128 + ((c < 128) ? 0 : 64);
        const float* wg   = (c < 128) ? (Wg0 + c) : (Wg1 + (c - 128));
        float m = 0.f;
        #pragma unroll
        for (int j = 0; j < 64; ++j)
            m += wrow[j] * wg[(long)j * 128];
        (dst + 98304)[pk256(d, c)] = f2bf(m);
    } else if (blk == 304) {                            // beff
        const int d = tid;
        const float* wrow = Wout + (long)d * 128;
        float s = bout[d];
        for (int j = 0; j < 64; ++j)
            s += wrow[j] * bg0[j] + wrow[64 + j] * bg1[j];
        beff[d] = s;
    } else {                                            // rope table
        const int idx = (blk - 305) * 256 + tid;        // 0..16383
        const int t = idx >> 3, k = idx & 7;
        const float theta = powf(10000.0f, -0.125f * (float)k);
        const float fr = (float)t * theta;
        rtab[idx] = make_float2(cosf(fr), sinf(fr));
    }
}

// ---------------- fused kernel: BM=16, 4 waves, 4 blocks/CU --------------
// grid = B*(T/16) = 512 blocks, 256 thr. Wave h:
//   QKV: Q head h (16 toks) + {K,V} half (sel=h>>1, mfh=h&1) interleaved.
//   Attention: head h (S^T = mfma(K,Q), softmax, P relayout, PV via V^T).
//   Out: single combined projection out = O @ M^T + beff (K=256).
__global__ __launch_bounds__(256) void fused_kernel(
    const float* __restrict__ H, const unsigned short* __restrict__ Wallb,
    const float* __restrict__ wq, const float* __restrict__ wk,
    const float* __restrict__ wv, const float2* __restrict__ rtab,
    const float* __restrict__ beff, float* __restrict__ out)
{
    __shared__ __align__(16) char smem[37888];
    char* lds_a = smem;            // [32][512B] H staging (16KB)  [phase A]
    char* o_lds = smem;            // [16][512B] O tile (8KB)      [reuse]
    char* q_lds = smem + 16384;    // 4 heads x [16][128B] (8KB)
    char* k_lds = smem + 24576;    // [32][128B] (4KB)
    char* v_t   = smem + 28672;    // V^T [64 ch][80B stride] (5KB)
    char* p_att = smem + 33792;    // 4 waves x 1KB

    const int tid = threadIdx.x;
    const int blk = blockIdx.x;
    const int b  = blk >> 7;
    const int t0 = (blk & 127) << 4;

    const unsigned short* Mpk = Wallb + 98304;

    // ---- stage H rows [t0-16, t0+16) (clamped), f32 -> bf16, swizzled ----
    for (int idx = tid; idx < 1024; idx += 256) {
        int row = idx >> 5, ch = idx & 31;
        int t = t0 - 16 + row; if (t < 0) t = 0;       // masked later
        const float4* s4 = (const float4*)(H + ((size_t)b * T_SEQ + t) * DMODEL + ch * 8);
        float4 a = s4[0], c = s4[1];
        ushort8 o;
        o[0] = f2bf(a.x); o[1] = f2bf(a.y); o[2] = f2bf(a.z); o[3] = f2bf(a.w);
        o[4] = f2bf(c.x); o[5] = f2bf(c.y); o[6] = f2bf(c.z); o[7] = f2bf(c.w);
        int byte = row * 512 + ch * 16;
        byte ^= (row & 7) << 4;
        *(ushort8*)(lds_a + byte) = o;
    }
    __syncthreads();

    const int h  = tid >> 6;       // wave = head
    const int l  = tid & 63;
    const int g  = l >> 4;
    const int li = l & 15;
    const int lane16 = l * 8;      // packed-W per-lane elem offset (16B/lane)

    const int sel = h >> 1;        // 0 = K, 1 = V
    const int mfh = h & 1;         // halo row half

    // ---- QKV: Q head h + K/V half, interleaved ---------------------------
    f32x4 accq[4] = {};
    f32x4 acckv[4] = {};
    #pragma unroll
    for (int ks = 0; ks < 8; ++ks) {
        const int rowq = 16 + li;
        int bq = rowq * 512 + (ks * 32 + g * 8) * 2;
        bq ^= (rowq & 7) << 4;
        bf16x8 aq = *(const bf16x8*)(lds_a + bq);
        const int rowk = mfh * 16 + li;
        int bk = rowk * 512 + (ks * 32 + g * 8) * 2;
        bk ^= (rowk & 7) << 4;
        bf16x8 akv = *(const bf16x8*)(lds_a + bk);
        #pragma unroll
        for (int nf = 0; nf < 4; ++nf) {
            bf16x8 bqf = *(const bf16x8*)(Wallb + (size_t)((h * 4 + nf) * 8 + ks) * 512 + lane16);
            accq[nf] = __builtin_amdgcn_mfma_f32_16x16x32_bf16(aq, bqf, accq[nf], 0, 0, 0);
            bf16x8 bkf = *(const bf16x8*)(Wallb + (size_t)((16 + sel * 4 + nf) * 8 + ks) * 512 + lane16);
            acckv[nf] = __builtin_amdgcn_mfma_f32_16x16x32_bf16(akv, bkf, acckv[nf], 0, 0, 0);
        }
    }

    // ---- Q epilogue: rmsnorm + rope -> q_lds[h] --------------------------
    {
        float gw[4];
        #pragma unroll
        for (int nf = 0; nf < 4; ++nf) gw[nf] = wq[h * 64 + nf * 16 + li];
        #pragma unroll
        for (int r = 0; r < 4; ++r) {
            float x0 = accq[0][r], x1 = accq[1][r];
            float x2 = accq[2][r], x3 = accq[3][r];
            float ss = x0 * x0 + x1 * x1 + x2 * x2 + x3 * x3;
            ss += __shfl_xor(ss, 1);
            ss += __shfl_xor(ss, 2);
            ss += __shfl_xor(ss, 4);
            ss += __shfl_xor(ss, 8);
            const float rinv = rsqrtf(ss * (1.0f / 64.0f) + 1e-8f);
            const int tok = g * 4 + r;
            const int t = t0 + tok;
            float v0 = x0 * rinv * gw[0];
            float v1 = x1 * rinv * gw[1];
            float v2 = x2 * rinv * gw[2];
            float v3 = x3 * rinv * gw[3];
            float2 cs = rtab[t * 8 + (li >> 1)];
            float px = __shfl_xor(v3, 1);
            v3 = ((li & 1) == 0) ? (v3 * cs.x - px * cs.y) : (px * cs.y + v3 * cs.x);
            char* qb = q_lds + h * 2048;
            const int sw = (tok & 7) << 4;
            *(unsigned short*)(qb + ((tok * 128 + (0 * 16 + li) * 2) ^ sw)) = f2bf(v0);
            *(unsigned short*)(qb + ((tok * 128 + (1 * 16 + li) * 2) ^ sw)) = f2bf(v1);
            *(unsigned short*)(qb + ((tok * 128 + (2 * 16 + li) * 2) ^ sw)) = f2bf(v2);
            *(unsigned short*)(qb + ((tok * 128 + (3 * 16 + li) * 2) ^ sw)) = f2bf(v3);
        }
    }

    // ---- K/V epilogue: rmsnorm + rope -> k_lds / v_t ---------------------
    {
        float gw[4];
        #pragma unroll
        for (int nf = 0; nf < 4; ++nf)
            gw[nf] = (sel == 0) ? wk[nf * 16 + li] : wv[nf * 16 + li];
        #pragma unroll
        for (int r = 0; r < 4; ++r) {
            float x0 = acckv[0][r], x1 = acckv[1][r];
            float x2 = acckv[2][r], x3 = acckv[3][r];
            float ss = x0 * x0 + x1 * x1 + x2 * x2 + x3 * x3;
            ss += __shfl_xor(ss, 1);
            ss += __shfl_xor(ss, 2);
            ss += __shfl_xor(ss, 4);
            ss += __shfl_xor(ss, 8);
            const float rinv = rsqrtf(ss * (1.0f / 64.0f) + 1e-8f);
            const int row = mfh * 16 + g * 4 + r;      // halo row 0..31
            int tk = t0 - 16 + row; if (tk < 0) tk = 0;
            float v0 = x0 * rinv * gw[0];
            float v1 = x1 * rinv * gw[1];
            float v2 = x2 * rinv * gw[2];
            float v3 = x3 * rinv * gw[3];
            float2 cs = rtab[tk * 8 + (li >> 1)];
            float px = __shfl_xor(v3, 1);
            v3 = ((li & 1) == 0) ? (v3 * cs.x - px * cs.y) : (px * cs.y + v3 * cs.x);
            if (sel == 0) {
                const int sw = (row & 7) << 4;
                *(unsigned short*)(k_lds + ((row * 128 + (0 * 16 + li) * 2) ^ sw)) = f2bf(v0);
                *(unsigned short*)(k_lds + ((row * 128 + (1 * 16 + li) * 2) ^ sw)) = f2bf(v1);
                *(unsigned short*)(k_lds + ((row * 128 + (2 * 16 + li) * 2) ^ sw)) = f2bf(v2);
                *(unsigned short*)(k_lds + ((row * 128 + (3 * 16 + li) * 2) ^ sw)) = f2bf(v3);
            } else {
                *(unsigned short*)(v_t + (0 * 16 + li) * 80 + row * 2) = f2bf(v0);
                *(unsigned short*)(v_t + (1 * 16 + li) * 80 + row * 2) = f2bf(v1);
                *(unsigned short*)(v_t + (2 * 16 + li) * 80 + row * 2) = f2bf(v2);
                *(unsigned short*)(v_t + (3 * 16 + li) * 80 + row * 2) = f2bf(v3);
            }
        }
    }
    __syncthreads();

    // ---- attention: head h -----------------------------------------------
    {
        bf16x8 qf0, qf1;
        {
            const char* qb = q_lds + h * 2048;
            const int sw = (li & 7) << 4;
            qf0 = *(const bf16x8*)(qb + ((li * 128 + g * 16) ^ sw));
            qf1 = *(const bf16x8*)(qb + ((li * 128 + 64 + g * 16) ^ sw));
        }
        f32x4 st[2];
        #pragma unroll
        for (int tile = 0; tile < 2; ++tile) {
            const int row = tile * 16 + li;
            const int sw = (row & 7) << 4;
            bf16x8 kf0 = *(const bf16x8*)(k_lds + ((row * 128 + g * 16) ^ sw));
            bf16x8 kf1 = *(const bf16x8*)(k_lds + ((row * 128 + 64 + g * 16) ^ sw));
            f32x4 acc = {};
            acc = __builtin_amdgcn_mfma_f32_16x16x32_bf16(kf0, qf0, acc, 0, 0, 0);
            acc = __builtin_amdgcn_mfma_f32_16x16x32_bf16(kf1, qf1, acc, 0, 0, 0);
            st[tile] = acc;
        }

        float p[8];
        float mx = -1e30f;
        #pragma unroll
        for (int tile = 0; tile < 2; ++tile) {
            #pragma unroll
            for (int r = 0; r < 4; ++r) {
                int krel = tile * 16 - 16 + g * 4 + r;
                int dd = li - krel;
                bool ok = ((unsigned)dd < 16u) && (t0 + krel >= 0);
                float v = ok ? st[tile][r] * 0.125f : -1e30f;
                p[tile * 4 + r] = v;
                mx = fmaxf(mx, v);
            }
        }
        mx = fmaxf(mx, __shfl_xor(mx, 16));
        mx = fmaxf(mx, __shfl_xor(mx, 32));
        float sum = 0.f;
        #pragma unroll
        for (int i = 0; i < 8; ++i) { p[i] = __expf(p[i] - mx); sum += p[i]; }
        sum += __shfl_xor(sum, 16);
        sum += __shfl_xor(sum, 32);
        const float inv = 1.0f / sum;

        // P -> wave-local LDS relayout to K=32 A-fragment
        bf16x8 paf;
        {
            char* pbase = p_att + h * 1024;
            uint2 w0, w1;
            w0.x = (unsigned)f2bf(p[0] * inv) | ((unsigned)f2bf(p[1] * inv) << 16);
            w0.y = (unsigned)f2bf(p[2] * inv) | ((unsigned)f2bf(p[3] * inv) << 16);
            w1.x = (unsigned)f2bf(p[4] * inv) | ((unsigned)f2bf(p[5] * inv) << 16);
            w1.y = (unsigned)f2bf(p[6] * inv) | ((unsigned)f2bf(p[7] * inv) << 16);
            const int sw = (li & 3) << 4;
            *(uint2*)(pbase + ((li * 64 + 0 * 32 + g * 8) ^ sw)) = w0;
            *(uint2*)(pbase + ((li * 64 + 1 * 32 + g * 8) ^ sw)) = w1;
            asm volatile("s_waitcnt lgkmcnt(0)" ::: "memory");
            paf = *(const bf16x8*)(pbase + ((li * 64 + g * 16) ^ sw));
        }

        // PV via V^T: single b128 B-frag per ctile
        f32x4 o[4] = {};
        #pragma unroll
        for (int ctile = 0; ctile < 4; ++ctile) {
            bf16x8 vf = *(const bf16x8*)(v_t + (ctile * 16 + li) * 80 + g * 16);
            o[ctile] = __builtin_amdgcn_mfma_f32_16x16x32_bf16(paf, vf, o[ctile], 0, 0, 0);
        }

        // inverse rope on chans 48..63 (ctile 3); write O to swizzled LDS
        #pragma unroll
        for (int r = 0; r < 4; ++r) {
            const int row = g * 4 + r;
            const int t = t0 + row;
            float o3 = o[3][r];
            float po = __shfl_xor(o3, 1);
            float2 cs = rtab[t * 8 + (li >> 1)];
            o3 = ((li & 1) == 0) ? (o3 * cs.x + po * cs.y) : (-po * cs.y + o3 * cs.x);
            #pragma unroll
            for (int ctile = 0; ctile < 4; ++ctile) {
                const int col = h * 64 + ctile * 16 + li;
                int byte = row * 512 + col * 2;
                byte ^= (row & 7) << 4;
                float val = (ctile == 3) ? o3 : o[ctile][r];
                *(unsigned short*)(o_lds + byte) = f2bf(val);
            }
        }
    }
    __syncthreads();

    // ---- combined out projection: out = O @ M^T + beff (K=256) -----------
    {
        f32x4 acco[4] = {};
        #pragma unroll
        for (int ks = 0; ks < 8; ++ks) {
            int byte = li * 512 + (ks * 32 + g * 8) * 2;
            byte ^= (li & 7) << 4;
            bf16x8 a = *(const bf16x8*)(o_lds + byte);
            #pragma unroll
            for (int nf = 0; nf < 4; ++nf) {
                const int colblk = h * 4 + nf;
                bf16x8 bfr = *(const bf16x8*)(Mpk + (size_t)(colblk * 8 + ks) * 512 + lane16);
                acco[nf] = __builtin_amdgcn_mfma_f32_16x16x32_bf16(a, bfr, acco[nf], 0, 0, 0);
            }
        }
        #pragma unroll
        for (int nf = 0; nf < 4; ++nf) {
            const int col = h * 64 + nf * 16 + li;
            const float bb = beff[col];
            #pragma unroll
            for (int r = 0; r < 4; ++r) {
                const int row = g * 4 + r;
                out[(size_t)(b * T_SEQ + t0 + row) * DMODEL + col] = acco[nf][r] + bb;
            }
        }
    }
}

extern "C" void kernel_launch(void* const* d_in, const int* in_sizes, int n_in,
                              void* d_out, int out_size, void* d_ws, size_t ws_size,
                              hipStream_t stream) {
    const float* H    = (const float*)d_in[0];
    const float* WQ   = (const float*)d_in[1];
    const float* WK   = (const float*)d_in[2];
    const float* WV   = (const float*)d_in[3];
    const float* wq   = (const float*)d_in[4];
    const float* wk   = (const float*)d_in[5];
    const float* wv   = (const float*)d_in[6];
    const float* Wg0  = (const float*)d_in[7];
    const float* bg0  = (const float*)d_in[8];
    const float* Wg1  = (const float*)d_in[9];
    const float* bg1  = (const float*)d_in[10];
    const float* Wout = (const float*)d_in[11];
    const float* bout = (const float*)d_in[12];
    float* out = (float*)d_out;

    char* ws = (char*)d_ws;
    unsigned short* Wallb = (unsigned short*)ws;          // 327,680 B (region1 + M)
    float* beff = (float*)(ws + 327680);                  //   1,024 B
    float2* rtab = (float2*)(ws + 331776);                // 131,072 B

    conv_w_kernel<<<369, 256, 0, stream>>>(WQ, WK, WV, Wg0, Wg1, Wout,
                                           bg0, bg1, bout, Wallb, beff, rtab);
    fused_kernel<<<B_SZ * T_SEQ / 16, 256, 0, stream>>>(H, Wallb, wq, wk, wv, rtab,
                                                        beff, out);
}

// Round 14
// 25.096 us; speedup vs baseline: 2.3935x; 1.0035x over previous
//
#include <hip/hip_runtime.h>
#include <math.h>

#define T_SEQ 2048
#define DMODEL 256
#define C_HEAD 64
#define NH 4
#define NWIN 16
#define B_SZ 4

typedef __attribute__((ext_vector_type(8))) short bf16x8;
typedef __attribute__((ext_vector_type(8))) unsigned short ushort8;
typedef __attribute__((ext_vector_type(4))) float f32x4;

static __device__ __forceinline__ unsigned short f2bf(float f) {
    union { float f; unsigned int u; } v; v.f = f;
    unsigned int r = v.u + 0x7FFFu + ((v.u >> 16) & 1u);
    return (unsigned short)(r >> 16);
}

// ---------------- conv_w: pack weights fragment-major + rope table ------
// Region 1 (K=256): cols [WQ(256) WK(64) WV(64)]; Region 2 (K=128):
// cols [Wg0(64) Wg1(64) Wout(256)] at +98304. Fragment-major: every MFMA
// B-load is base + lane*16B. blocks 72..135: rope table (cos,sin).
__global__ __launch_bounds__(256) void conv_w_kernel(
    const float* __restrict__ WQ, const float* __restrict__ WK,
    const float* __restrict__ WV, const float* __restrict__ Wg0,
    const float* __restrict__ Wg1, const float* __restrict__ Wout,
    unsigned short* __restrict__ dst, float2* __restrict__ rtab) {
    const int tid = threadIdx.x;
    if (blockIdx.x >= 72) {
        const int idx = (blockIdx.x - 72) * 256 + tid;   // 0..16383
        const int t = idx >> 3, k = idx & 7;
        const float theta = powf(10000.0f, -0.125f * (float)k);
        const float fr = (float)t * theta;
        rtab[idx] = make_float2(cosf(fr), sinf(fr));
        return;
    }
    const int i = blockIdx.x * 256 + tid;               // 18432 vec8
    const float* s; long off; long doff;
    if (i < 12288) {                                    // K=256 region
        const long e = (long)i * 8;
        const int col = (int)(e >> 8), k = (int)(e & 255);
        if      (col < 256) { s = WQ; off = (long)col * 256 + k; }
        else if (col < 320) { s = WK; off = (long)(col - 256) * 256 + k; }
        else                { s = WV; off = (long)(col - 320) * 256 + k; }
        doff = ((long)(col >> 4) * 8 + (k >> 5)) * 512 + ((k >> 3) & 3) * 128 + (col & 15) * 8;
    } else {                                            // K=128 region
        const long e = (long)(i - 12288) * 8;
        const int col = (int)(e >> 7), k = (int)(e & 127);
        if      (col < 64)  { s = Wg0; off = (long)col * 128 + k; }
        else if (col < 128) { s = Wg1; off = (long)(col - 64) * 128 + k; }
        else                { s = Wout; off = (long)(col - 128) * 128 + k; }
        doff = 98304 + ((long)(col >> 4) * 4 + (k >> 5)) * 512 + ((k >> 3) & 3) * 128 + (col & 15) * 8;
    }
    const float4* s4 = (const float4*)(s + off);
    float4 a = s4[0], b = s4[1];
    ushort8 o;
    o[0] = f2bf(a.x); o[1] = f2bf(a.y); o[2] = f2bf(a.z); o[3] = f2bf(a.w);
    o[4] = f2bf(b.x); o[5] = f2bf(b.y); o[6] = f2bf(b.z); o[7] = f2bf(b.w);
    *(ushort8*)(dst + doff) = o;
}

// ---------------- fused kernel: 2-tile software pipeline ----------------
// grid = B*(T/32) = 256 blocks, 512 thr (8 waves). Each block owns tiles
// A = [t0A, t0A+16) and B = A+16, each with its own LDS context (37888 B).
// Phases: stageA | qkvA+stageB | attnA+qkvB | gatesA+attnB | outA+gatesB
// | outB  (6 barriers for 2 tiles vs 10 unpipelined; attn-phase idle
// waves now run the other tile's QKV; HBM stage hides under MFMA).
__global__ __launch_bounds__(512) void fused_kernel(
    const float* __restrict__ H, const unsigned short* __restrict__ Wallb,
    const float* __restrict__ wq, const float* __restrict__ wk,
    const float* __restrict__ wv, const float2* __restrict__ rtab,
    const float* __restrict__ bg0, const float* __restrict__ bg1,
    const float* __restrict__ bout, float* __restrict__ out)
{
    // per-context layout (offsets from ctx base):
    //   +0     [32][512B] H staging (16KB)  -> overlaid after qkv by:
    //   +0     [16][512B] o_lds (8KB), +8192 [16][256B] p_lds (4KB)
    //   +16384 q_lds: 4 heads x [16][128B] (8KB)
    //   +24576 k_lds: [32][128B] (4KB)
    //   +28672 v_t:   V^T [64ch][80B] (5KB)
    //   +33792 p_att: 4 waves x 1KB (4KB)   -> ctx size 37888
    __shared__ __align__(16) char smem[75776];
    const int tid = threadIdx.x;
    const int blk = blockIdx.x;
    const int b   = blk >> 6;
    const int t0A = (blk & 63) << 5;
    const int t0B = t0A + 16;
    char* ctxA = smem;
    char* ctxB = smem + 37888;

    const unsigned short* Wpk2 = Wallb + 98304;   // K=128 packed region

    const int w  = tid >> 6;       // wave 0..7
    const int l  = tid & 63;
    const int g  = l >> 4;
    const int li = l & 15;
    const int lane16 = l * 8;      // packed-W per-lane elem offset (16B/lane)

    // ---------------- phase jobs ----------------
    auto stage_load = [&](int t0, float4 sb[2][2]) {
        #pragma unroll
        for (int it = 0; it < 2; ++it) {
            const int idx = tid + it * 512;
            const int row = idx >> 5, ch = idx & 31;
            int t = t0 - 16 + row; if (t < 0) t = 0;   // masked later
            const float4* s4 = (const float4*)(H + ((size_t)b * T_SEQ + t) * DMODEL + ch * 8);
            sb[it][0] = s4[0];
            sb[it][1] = s4[1];
        }
    };
    auto stage_write = [&](char* ctx, float4 sb[2][2]) {
        #pragma unroll
        for (int it = 0; it < 2; ++it) {
            const int idx = tid + it * 512;
            const int row = idx >> 5, ch = idx & 31;
            ushort8 o;
            o[0] = f2bf(sb[it][0].x); o[1] = f2bf(sb[it][0].y);
            o[2] = f2bf(sb[it][0].z); o[3] = f2bf(sb[it][0].w);
            o[4] = f2bf(sb[it][1].x); o[5] = f2bf(sb[it][1].y);
            o[6] = f2bf(sb[it][1].z); o[7] = f2bf(sb[it][1].w);
            int byte = row * 512 + ch * 16;
            byte ^= (row & 7) << 4;
            *(ushort8*)(ctx + byte) = o;
        }
    };

    auto qkv = [&](char* ctx, int t0) {
        char* q_lds = ctx + 16384;
        char* k_lds = ctx + 24576;
        char* v_t   = ctx + 28672;
        if (w < 4) {
            f32x4 acc[4] = {};
            #pragma unroll
            for (int ks = 0; ks < 8; ++ks) {
                const int row = 16 + li;               // tokens t0..t0+15
                int byte = row * 512 + (ks * 32 + g * 8) * 2;
                byte ^= (row & 7) << 4;
                bf16x8 a = *(const bf16x8*)(ctx + byte);
                #pragma unroll
                for (int nf = 0; nf < 4; ++nf) {
                    bf16x8 bq = *(const bf16x8*)(Wallb + (size_t)((w * 4 + nf) * 8 + ks) * 512 + lane16);
                    acc[nf] = __builtin_amdgcn_mfma_f32_16x16x32_bf16(a, bq, acc[nf], 0, 0, 0);
                }
            }
            float gw[4];
            #pragma unroll
            for (int nf = 0; nf < 4; ++nf) gw[nf] = wq[w * 64 + nf * 16 + li];
            #pragma unroll
            for (int r = 0; r < 4; ++r) {
                float x0 = acc[0][r], x1 = acc[1][r];
                float x2 = acc[2][r], x3 = acc[3][r];
                float ss = x0 * x0 + x1 * x1 + x2 * x2 + x3 * x3;
                ss += __shfl_xor(ss, 1);
                ss += __shfl_xor(ss, 2);
                ss += __shfl_xor(ss, 4);
                ss += __shfl_xor(ss, 8);
                const float rinv = rsqrtf(ss * (1.0f / 64.0f) + 1e-8f);
                const int tok = g * 4 + r;
                const int t = t0 + tok;
                float v0 = x0 * rinv * gw[0];
                float v1 = x1 * rinv * gw[1];
                float v2 = x2 * rinv * gw[2];
                float v3 = x3 * rinv * gw[3];
                float2 cs = rtab[t * 8 + (li >> 1)];
                float px = __shfl_xor(v3, 1);
                v3 = ((li & 1) == 0) ? (v3 * cs.x - px * cs.y) : (px * cs.y + v3 * cs.x);
                char* qb = q_lds + w * 2048;
                const int sw = (tok & 7) << 4;
                *(unsigned short*)(qb + ((tok * 128 + (0 * 16 + li) * 2) ^ sw)) = f2bf(v0);
                *(unsigned short*)(qb + ((tok * 128 + (1 * 16 + li) * 2) ^ sw)) = f2bf(v1);
                *(unsigned short*)(qb + ((tok * 128 + (2 * 16 + li) * 2) ^ sw)) = f2bf(v2);
                *(unsigned short*)(qb + ((tok * 128 + (3 * 16 + li) * 2) ^ sw)) = f2bf(v3);
            }
        } else {
            const int sel = (w - 4) >> 1;      // 0 = K, 1 = V
            const int mfh = (w - 4) & 1;       // halo row half
            f32x4 acc[4] = {};
            #pragma unroll
            for (int ks = 0; ks < 8; ++ks) {
                const int row = mfh * 16 + li;
                int byte = row * 512 + (ks * 32 + g * 8) * 2;
                byte ^= (row & 7) << 4;
                bf16x8 a = *(const bf16x8*)(ctx + byte);
                #pragma unroll
                for (int nf = 0; nf < 4; ++nf) {
                    bf16x8 bkv = *(const bf16x8*)(Wallb + (size_t)((16 + sel * 4 + nf) * 8 + ks) * 512 + lane16);
                    acc[nf] = __builtin_amdgcn_mfma_f32_16x16x32_bf16(a, bkv, acc[nf], 0, 0, 0);
                }
            }
            float gw[4];
            #pragma unroll
            for (int nf = 0; nf < 4; ++nf)
                gw[nf] = (sel == 0) ? wk[nf * 16 + li] : wv[nf * 16 + li];
            #pragma unroll
            for (int r = 0; r < 4; ++r) {
                float x0 = acc[0][r], x1 = acc[1][r];
                float x2 = acc[2][r], x3 = acc[3][r];
                float ss = x0 * x0 + x1 * x1 + x2 * x2 + x3 * x3;
                ss += __shfl_xor(ss, 1);
                ss += __shfl_xor(ss, 2);
                ss += __shfl_xor(ss, 4);
                ss += __shfl_xor(ss, 8);
                const float rinv = rsqrtf(ss * (1.0f / 64.0f) + 1e-8f);
                const int row = mfh * 16 + g * 4 + r;      // halo row 0..31
                int tk = t0 - 16 + row; if (tk < 0) tk = 0;
                float v0 = x0 * rinv * gw[0];
                float v1 = x1 * rinv * gw[1];
                float v2 = x2 * rinv * gw[2];
                float v3 = x3 * rinv * gw[3];
                float2 cs = rtab[tk * 8 + (li >> 1)];
                float px = __shfl_xor(v3, 1);
                v3 = ((li & 1) == 0) ? (v3 * cs.x - px * cs.y) : (px * cs.y + v3 * cs.x);
                if (sel == 0) {
                    const int sw = (row & 7) << 4;
                    *(unsigned short*)(k_lds + ((row * 128 + (0 * 16 + li) * 2) ^ sw)) = f2bf(v0);
                    *(unsigned short*)(k_lds + ((row * 128 + (1 * 16 + li) * 2) ^ sw)) = f2bf(v1);
                    *(unsigned short*)(k_lds + ((row * 128 + (2 * 16 + li) * 2) ^ sw)) = f2bf(v2);
                    *(unsigned short*)(k_lds + ((row * 128 + (3 * 16 + li) * 2) ^ sw)) = f2bf(v3);
                } else {
                    *(unsigned short*)(v_t + (0 * 16 + li) * 80 + row * 2) = f2bf(v0);
                    *(unsigned short*)(v_t + (1 * 16 + li) * 80 + row * 2) = f2bf(v1);
                    *(unsigned short*)(v_t + (2 * 16 + li) * 80 + row * 2) = f2bf(v2);
                    *(unsigned short*)(v_t + (3 * 16 + li) * 80 + row * 2) = f2bf(v3);
                }
            }
        }
    };

    auto attn = [&](char* ctx, int t0) {
        if (w >= 4) return;
        char* o_lds = ctx;
        char* q_lds = ctx + 16384;
        char* k_lds = ctx + 24576;
        char* v_t   = ctx + 28672;
        char* p_att = ctx + 33792;
        const int h = w;
        bf16x8 qf0, qf1;
        {
            const char* qb = q_lds + h * 2048;
            const int sw = (li & 7) << 4;
            qf0 = *(const bf16x8*)(qb + ((li * 128 + g * 16) ^ sw));
            qf1 = *(const bf16x8*)(qb + ((li * 128 + 64 + g * 16) ^ sw));
        }
        f32x4 st[2];
        #pragma unroll
        for (int tile = 0; tile < 2; ++tile) {
            const int row = tile * 16 + li;
            const int sw = (row & 7) << 4;
            bf16x8 kf0 = *(const bf16x8*)(k_lds + ((row * 128 + g * 16) ^ sw));
            bf16x8 kf1 = *(const bf16x8*)(k_lds + ((row * 128 + 64 + g * 16) ^ sw));
            f32x4 acc = {};
            acc = __builtin_amdgcn_mfma_f32_16x16x32_bf16(kf0, qf0, acc, 0, 0, 0);
            acc = __builtin_amdgcn_mfma_f32_16x16x32_bf16(kf1, qf1, acc, 0, 0, 0);
            st[tile] = acc;
        }
        float p[8];
        float mx = -1e30f;
        #pragma unroll
        for (int tile = 0; tile < 2; ++tile) {
            #pragma unroll
            for (int r = 0; r < 4; ++r) {
                int krel = tile * 16 - 16 + g * 4 + r;
                int dd = li - krel;
                bool ok = ((unsigned)dd < 16u) && (t0 + krel >= 0);
                float v = ok ? st[tile][r] * 0.125f : -1e30f;
                p[tile * 4 + r] = v;
                mx = fmaxf(mx, v);
            }
        }
        mx = fmaxf(mx, __shfl_xor(mx, 16));
        mx = fmaxf(mx, __shfl_xor(mx, 32));
        float sum = 0.f;
        #pragma unroll
        for (int i = 0; i < 8; ++i) { p[i] = __expf(p[i] - mx); sum += p[i]; }
        sum += __shfl_xor(sum, 16);
        sum += __shfl_xor(sum, 32);
        const float inv = 1.0f / sum;

        bf16x8 paf;
        {
            char* pbase = p_att + h * 1024;
            uint2 w0, w1;
            w0.x = (unsigned)f2bf(p[0] * inv) | ((unsigned)f2bf(p[1] * inv) << 16);
            w0.y = (unsigned)f2bf(p[2] * inv) | ((unsigned)f2bf(p[3] * inv) << 16);
            w1.x = (unsigned)f2bf(p[4] * inv) | ((unsigned)f2bf(p[5] * inv) << 16);
            w1.y = (unsigned)f2bf(p[6] * inv) | ((unsigned)f2bf(p[7] * inv) << 16);
            const int sw = (li & 3) << 4;
            *(uint2*)(pbase + ((li * 64 + 0 * 32 + g * 8) ^ sw)) = w0;
            *(uint2*)(pbase + ((li * 64 + 1 * 32 + g * 8) ^ sw)) = w1;
            asm volatile("s_waitcnt lgkmcnt(0)" ::: "memory");
            paf = *(const bf16x8*)(pbase + ((li * 64 + g * 16) ^ sw));
        }

        f32x4 o[4] = {};
        #pragma unroll
        for (int ctile = 0; ctile < 4; ++ctile) {
            bf16x8 vf = *(const bf16x8*)(v_t + (ctile * 16 + li) * 80 + g * 16);
            o[ctile] = __builtin_amdgcn_mfma_f32_16x16x32_bf16(paf, vf, o[ctile], 0, 0, 0);
        }

        #pragma unroll
        for (int r = 0; r < 4; ++r) {
            const int row = g * 4 + r;
            const int t = t0 + row;
            float o3 = o[3][r];
            float po = __shfl_xor(o3, 1);
            float2 cs = rtab[t * 8 + (li >> 1)];
            o3 = ((li & 1) == 0) ? (o3 * cs.x + po * cs.y) : (-po * cs.y + o3 * cs.x);
            #pragma unroll
            for (int ctile = 0; ctile < 4; ++ctile) {
                const int col = h * 64 + ctile * 16 + li;
                int byte = row * 512 + col * 2;
                byte ^= (row & 7) << 4;
                float val = (ctile == 3) ? o3 : o[ctile][r];
                *(unsigned short*)(o_lds + byte) = f2bf(val);
            }
        }
    };

    auto gates = [&](char* ctx) {
        char* o_lds = ctx;
        char* p_lds = ctx + 8192;
        const int gate = w >> 2, colq = w & 3;
        const float* bg = gate ? bg1 : bg0;
        f32x4 accp = {};
        #pragma unroll
        for (int ks = 0; ks < 4; ++ks) {
            int byte = li * 512 + (gate * 128 + ks * 32 + g * 8) * 2;
            byte ^= (li & 7) << 4;
            bf16x8 a = *(const bf16x8*)(o_lds + byte);
            const int colblk = gate * 4 + colq;
            bf16x8 bfr = *(const bf16x8*)(Wpk2 + (size_t)(colblk * 4 + ks) * 512 + lane16);
            accp = __builtin_amdgcn_mfma_f32_16x16x32_bf16(a, bfr, accp, 0, 0, 0);
        }
        const int cl = colq * 16 + li;
        const int pcol = gate * 64 + cl;
        const float bb = bg[cl];
        #pragma unroll
        for (int r = 0; r < 4; ++r) {
            const int row = g * 4 + r;
            int byte = row * 256 + pcol * 2;
            byte ^= (row & 7) << 4;
            *(unsigned short*)(p_lds + byte) = f2bf(accp[r] + bb);
        }
    };

    auto outp = [&](char* ctx, int t0) {
        char* p_lds = ctx + 8192;
        f32x4 acco[2] = {};
        #pragma unroll
        for (int ks = 0; ks < 4; ++ks) {
            int byte = li * 256 + (ks * 32 + g * 8) * 2;
            byte ^= (li & 7) << 4;
            bf16x8 a = *(const bf16x8*)(p_lds + byte);
            #pragma unroll
            for (int nf = 0; nf < 2; ++nf) {
                const int colblk = 8 + w * 2 + nf;             // Wout at col 128
                bf16x8 bfr = *(const bf16x8*)(Wpk2 + (size_t)(colblk * 4 + ks) * 512 + lane16);
                acco[nf] = __builtin_amdgcn_mfma_f32_16x16x32_bf16(a, bfr, acco[nf], 0, 0, 0);
            }
        }
        #pragma unroll
        for (int nf = 0; nf < 2; ++nf) {
            const int col = w * 32 + nf * 16 + li;
            const float bb = bout[col];
            #pragma unroll
            for (int r = 0; r < 4; ++r) {
                const int row = g * 4 + r;
                out[(size_t)(b * T_SEQ + t0 + row) * DMODEL + col] = acco[nf][r] + bb;
            }
        }
    };

    // ---------------- pipeline ----------------
    float4 sb[2][2];
    // P0: stage A
    stage_load(t0A, sb);
    stage_write(ctxA, sb);
    __syncthreads();
    // P1: qkv A  +  stage B (loads issued first, written after compute)
    stage_load(t0B, sb);
    qkv(ctxA, t0A);
    stage_write(ctxB, sb);
    __syncthreads();
    // P2: attn A (waves 0-3)  +  qkv B (all waves)
    attn(ctxA, t0A);
    qkv(ctxB, t0B);
    __syncthreads();
    // P3: gates A  +  attn B
    gates(ctxA);
    attn(ctxB, t0B);
    __syncthreads();
    // P4: out A  +  gates B
    outp(ctxA, t0A);
    gates(ctxB);
    __syncthreads();
    // P5: out B
    outp(ctxB, t0B);
}

extern "C" void kernel_launch(void* const* d_in, const int* in_sizes, int n_in,
                              void* d_out, int out_size, void* d_ws, size_t ws_size,
                              hipStream_t stream) {
    const float* H    = (const float*)d_in[0];
    const float* WQ   = (const float*)d_in[1];
    const float* WK   = (const float*)d_in[2];
    const float* WV   = (const float*)d_in[3];
    const float* wq   = (const float*)d_in[4];
    const float* wk   = (const float*)d_in[5];
    const float* wv   = (const float*)d_in[6];
    const float* Wg0  = (const float*)d_in[7];
    const float* bg0  = (const float*)d_in[8];
    const float* Wg1  = (const float*)d_in[9];
    const float* bg1  = (const float*)d_in[10];
    const float* Wout = (const float*)d_in[11];
    const float* bout = (const float*)d_in[12];
    float* out = (float*)d_out;

    char* ws = (char*)d_ws;
    unsigned short* Wallb = (unsigned short*)ws;          // 294,912 B
    float2* rtab = (float2*)(ws + 294912);                // 131,072 B

    conv_w_kernel<<<136, 256, 0, stream>>>(WQ, WK, WV, Wg0, Wg1, Wout, Wallb, rtab);
    fused_kernel<<<B_SZ * T_SEQ / 32, 512, 0, stream>>>(H, Wallb, wq, wk, wv, rtab,
                                                        bg0, bg1, bout, out);
}

// Round 15
// 22.384 us; speedup vs baseline: 2.6835x; 1.1212x over previous
//
#include <hip/hip_runtime.h>
#include <math.h>

#define T_SEQ 2048
#define DMODEL 256
#define C_HEAD 64
#define NH 4
#define NWIN 16
#define B_SZ 4

typedef __attribute__((ext_vector_type(8))) short bf16x8;
typedef __attribute__((ext_vector_type(8))) unsigned short ushort8;
typedef __attribute__((ext_vector_type(4))) float f32x4;

// barrier WITHOUT vmcnt drain: cross-wave comm is LDS-only, so only
// lgkmcnt(0) is required for correctness; in-flight global loads survive.
#define BAR() asm volatile("s_waitcnt lgkmcnt(0)\n\ts_barrier" ::: "memory")

static __device__ __forceinline__ unsigned short f2bf(float f) {
    union { float f; unsigned int u; } v; v.f = f;
    unsigned int r = v.u + 0x7FFFu + ((v.u >> 16) & 1u);
    return (unsigned short)(r >> 16);
}

// ---------------- conv_w: pack weights fragment-major + rope table ------
__global__ __launch_bounds__(256) void conv_w_kernel(
    const float* __restrict__ WQ, const float* __restrict__ WK,
    const float* __restrict__ WV, const float* __restrict__ Wg0,
    const float* __restrict__ Wg1, const float* __restrict__ Wout,
    unsigned short* __restrict__ dst, float2* __restrict__ rtab) {
    const int tid = threadIdx.x;
    if (blockIdx.x >= 72) {
        const int idx = (blockIdx.x - 72) * 256 + tid;   // 0..16383
        const int t = idx >> 3, k = idx & 7;
        const float theta = powf(10000.0f, -0.125f * (float)k);
        const float fr = (float)t * theta;
        rtab[idx] = make_float2(cosf(fr), sinf(fr));
        return;
    }
    const int i = blockIdx.x * 256 + tid;               // 18432 vec8
    const float* s; long off; long doff;
    if (i < 12288) {                                    // K=256 region
        const long e = (long)i * 8;
        const int col = (int)(e >> 8), k = (int)(e & 255);
        if      (col < 256) { s = WQ; off = (long)col * 256 + k; }
        else if (col < 320) { s = WK; off = (long)(col - 256) * 256 + k; }
        else                { s = WV; off = (long)(col - 320) * 256 + k; }
        doff = ((long)(col >> 4) * 8 + (k >> 5)) * 512 + ((k >> 3) & 3) * 128 + (col & 15) * 8;
    } else {                                            // K=128 region
        const long e = (long)(i - 12288) * 8;
        const int col = (int)(e >> 7), k = (int)(e & 127);
        if      (col < 64)  { s = Wg0; off = (long)col * 128 + k; }
        else if (col < 128) { s = Wg1; off = (long)(col - 64) * 128 + k; }
        else                { s = Wout; off = (long)(col - 128) * 128 + k; }
        doff = 98304 + ((long)(col >> 4) * 4 + (k >> 5)) * 512 + ((k >> 3) & 3) * 128 + (col & 15) * 8;
    }
    const float4* s4 = (const float4*)(s + off);
    float4 a = s4[0], b = s4[1];
    ushort8 o;
    o[0] = f2bf(a.x); o[1] = f2bf(a.y); o[2] = f2bf(a.z); o[3] = f2bf(a.w);
    o[4] = f2bf(b.x); o[5] = f2bf(b.y); o[6] = f2bf(b.z); o[7] = f2bf(b.w);
    *(ushort8*)(dst + doff) = o;
}

// ---------------- fused kernel: BM=16, 8 waves, counted barriers --------
// grid = B*(T/16) = 512 blocks, 512 thr (2 blocks/CU = 16 waves/CU).
// Waves 0-3: Q heads; waves 4-7: K/V halves. Next-phase weight fragments
// are issued BEFORE each barrier (barriers don't drain vmcnt), so phase
// transitions stop serializing L2 latency.
__global__ __launch_bounds__(512) void fused_kernel(
    const float* __restrict__ H, const unsigned short* __restrict__ Wallb,
    const float* __restrict__ wq, const float* __restrict__ wk,
    const float* __restrict__ wv, const float2* __restrict__ rtab,
    const float* __restrict__ bg0, const float* __restrict__ bg1,
    const float* __restrict__ bout, float* __restrict__ out)
{
    __shared__ __align__(16) char smem[37888];
    char* lds_a = smem;            // [32][512B] H staging (16KB)  [phase A]
    char* o_lds = smem;            // [16][512B] O tile (8KB)      [reuse]
    char* p_lds = smem + 8192;     // [16][256B] p tile (4KB)      [reuse]
    char* q_lds = smem + 16384;    // 4 heads x [16][128B] (8KB)
    char* k_lds = smem + 24576;    // [32][128B] (4KB)
    char* v_t   = smem + 28672;    // V^T [64 ch][80B stride] (5KB)
    char* p_att = smem + 33792;    // 4 waves x 1KB

    const int tid = threadIdx.x;
    const int blk = blockIdx.x;
    const int b  = blk >> 7;
    const int t0 = (blk & 127) << 4;

    const unsigned short* Wpk2 = Wallb + 98304;   // K=128 packed region

    const int w  = tid >> 6;       // wave 0..7
    const int l  = tid & 63;
    const int g  = l >> 4;
    const int li = l & 15;
    const int lane16 = l * 8;      // packed-W per-lane elem offset (16B/lane)

    // unified qkv geometry: waves 0-3 Q heads; 4-7 K/V halves
    const int cb0  = (w < 4) ? (w * 4) : (16 + ((w - 4) >> 1) * 4);
    const int rowa = (w < 4) ? (16 + li) : (((w - 4) & 1) * 16 + li);
    const int sel  = (w - 4) >> 1;     // 0=K 1=V (valid for w>=4)
    const int mfh  = (w - 4) & 1;

#define WFRAG(nf, ks) (*(const bf16x8*)(Wallb + (size_t)((cb0 + (nf)) * 8 + (ks)) * 512 + lane16))

    // ---- phase 0: stage H rows [t0-16,t0+16) + prefetch qkv ks=0,1 ------
    for (int idx = tid; idx < 1024; idx += 512) {
        int row = idx >> 5, ch = idx & 31;
        int t = t0 - 16 + row; if (t < 0) t = 0;       // masked later
        const float4* s4 = (const float4*)(H + ((size_t)b * T_SEQ + t) * DMODEL + ch * 8);
        float4 a = s4[0], c = s4[1];
        ushort8 o;
        o[0] = f2bf(a.x); o[1] = f2bf(a.y); o[2] = f2bf(a.z); o[3] = f2bf(a.w);
        o[4] = f2bf(c.x); o[5] = f2bf(c.y); o[6] = f2bf(c.z); o[7] = f2bf(c.w);
        int byte = row * 512 + ch * 16;
        byte ^= (row & 7) << 4;
        *(ushort8*)(lds_a + byte) = o;
    }
    bf16x8 cur[4], nxt[4];
    #pragma unroll
    for (int nf = 0; nf < 4; ++nf) { cur[nf] = WFRAG(nf, 0); nxt[nf] = WFRAG(nf, 1); }
    BAR();

    // ---- phase 1: qkv with 2-deep rolling weight prefetch ---------------
    f32x4 acc[4] = {};
    #pragma unroll
    for (int ks = 0; ks < 8; ++ks) {
        bf16x8 fut[4];
        if (ks < 6) {
            #pragma unroll
            for (int nf = 0; nf < 4; ++nf) fut[nf] = WFRAG(nf, ks + 2);
        }
        int abyte = rowa * 512 + (ks * 32 + g * 8) * 2;
        abyte ^= (rowa & 7) << 4;
        bf16x8 a = *(const bf16x8*)(lds_a + abyte);
        #pragma unroll
        for (int nf = 0; nf < 4; ++nf)
            acc[nf] = __builtin_amdgcn_mfma_f32_16x16x32_bf16(a, cur[nf], acc[nf], 0, 0, 0);
        #pragma unroll
        for (int nf = 0; nf < 4; ++nf) { cur[nf] = nxt[nf]; nxt[nf] = fut[nf]; }
    }

    // epilogues: rmsnorm + rope -> LDS
    if (w < 4) {
        float gw[4];
        #pragma unroll
        for (int nf = 0; nf < 4; ++nf) gw[nf] = wq[w * 64 + nf * 16 + li];
        #pragma unroll
        for (int r = 0; r < 4; ++r) {
            float x0 = acc[0][r], x1 = acc[1][r];
            float x2 = acc[2][r], x3 = acc[3][r];
            float ss = x0 * x0 + x1 * x1 + x2 * x2 + x3 * x3;
            ss += __shfl_xor(ss, 1);
            ss += __shfl_xor(ss, 2);
            ss += __shfl_xor(ss, 4);
            ss += __shfl_xor(ss, 8);
            const float rinv = rsqrtf(ss * (1.0f / 64.0f) + 1e-8f);
            const int tok = g * 4 + r;
            const int t = t0 + tok;
            float v0 = x0 * rinv * gw[0];
            float v1 = x1 * rinv * gw[1];
            float v2 = x2 * rinv * gw[2];
            float v3 = x3 * rinv * gw[3];
            float2 cs = rtab[t * 8 + (li >> 1)];
            float px = __shfl_xor(v3, 1);
            v3 = ((li & 1) == 0) ? (v3 * cs.x - px * cs.y) : (px * cs.y + v3 * cs.x);
            char* qb = q_lds + w * 2048;
            const int sw = (tok & 7) << 4;
            *(unsigned short*)(qb + ((tok * 128 + (0 * 16 + li) * 2) ^ sw)) = f2bf(v0);
            *(unsigned short*)(qb + ((tok * 128 + (1 * 16 + li) * 2) ^ sw)) = f2bf(v1);
            *(unsigned short*)(qb + ((tok * 128 + (2 * 16 + li) * 2) ^ sw)) = f2bf(v2);
            *(unsigned short*)(qb + ((tok * 128 + (3 * 16 + li) * 2) ^ sw)) = f2bf(v3);
        }
    } else {
        float gw[4];
        #pragma unroll
        for (int nf = 0; nf < 4; ++nf)
            gw[nf] = (sel == 0) ? wk[nf * 16 + li] : wv[nf * 16 + li];
        #pragma unroll
        for (int r = 0; r < 4; ++r) {
            float x0 = acc[0][r], x1 = acc[1][r];
            float x2 = acc[2][r], x3 = acc[3][r];
            float ss = x0 * x0 + x1 * x1 + x2 * x2 + x3 * x3;
            ss += __shfl_xor(ss, 1);
            ss += __shfl_xor(ss, 2);
            ss += __shfl_xor(ss, 4);
            ss += __shfl_xor(ss, 8);
            const float rinv = rsqrtf(ss * (1.0f / 64.0f) + 1e-8f);
            const int row = mfh * 16 + g * 4 + r;      // halo row 0..31
            int tk = t0 - 16 + row; if (tk < 0) tk = 0;
            float v0 = x0 * rinv * gw[0];
            float v1 = x1 * rinv * gw[1];
            float v2 = x2 * rinv * gw[2];
            float v3 = x3 * rinv * gw[3];
            float2 cs = rtab[tk * 8 + (li >> 1)];
            float px = __shfl_xor(v3, 1);
            v3 = ((li & 1) == 0) ? (v3 * cs.x - px * cs.y) : (px * cs.y + v3 * cs.x);
            if (sel == 0) {
                const int sw = (row & 7) << 4;
                *(unsigned short*)(k_lds + ((row * 128 + (0 * 16 + li) * 2) ^ sw)) = f2bf(v0);
                *(unsigned short*)(k_lds + ((row * 128 + (1 * 16 + li) * 2) ^ sw)) = f2bf(v1);
                *(unsigned short*)(k_lds + ((row * 128 + (2 * 16 + li) * 2) ^ sw)) = f2bf(v2);
                *(unsigned short*)(k_lds + ((row * 128 + (3 * 16 + li) * 2) ^ sw)) = f2bf(v3);
            } else {
                *(unsigned short*)(v_t + (0 * 16 + li) * 80 + row * 2) = f2bf(v0);
                *(unsigned short*)(v_t + (1 * 16 + li) * 80 + row * 2) = f2bf(v1);
                *(unsigned short*)(v_t + (2 * 16 + li) * 80 + row * 2) = f2bf(v2);
                *(unsigned short*)(v_t + (3 * 16 + li) * 80 + row * 2) = f2bf(v3);
            }
        }
    }
    BAR();

    // ---- phase 2: attention (waves 0-3); waves 4-7 prefetch gates W -----
    const int gate = w >> 2, colq = w & 3;
    bf16x8 gpre[4];
    if (w >= 4) {
        #pragma unroll
        for (int ks = 0; ks < 4; ++ks)
            gpre[ks] = *(const bf16x8*)(Wpk2 + (size_t)((gate * 4 + colq) * 4 + ks) * 512 + lane16);
    }
    if (w < 4) {
        const int h = w;
        bf16x8 qf0, qf1;
        {
            const char* qb = q_lds + h * 2048;
            const int sw = (li & 7) << 4;
            qf0 = *(const bf16x8*)(qb + ((li * 128 + g * 16) ^ sw));
            qf1 = *(const bf16x8*)(qb + ((li * 128 + 64 + g * 16) ^ sw));
        }
        f32x4 st[2];
        #pragma unroll
        for (int tile = 0; tile < 2; ++tile) {
            const int row = tile * 16 + li;
            const int sw = (row & 7) << 4;
            bf16x8 kf0 = *(const bf16x8*)(k_lds + ((row * 128 + g * 16) ^ sw));
            bf16x8 kf1 = *(const bf16x8*)(k_lds + ((row * 128 + 64 + g * 16) ^ sw));
            f32x4 sa = {};
            sa = __builtin_amdgcn_mfma_f32_16x16x32_bf16(kf0, qf0, sa, 0, 0, 0);
            sa = __builtin_amdgcn_mfma_f32_16x16x32_bf16(kf1, qf1, sa, 0, 0, 0);
            st[tile] = sa;
        }

        float p[8];
        float mx = -1e30f;
        #pragma unroll
        for (int tile = 0; tile < 2; ++tile) {
            #pragma unroll
            for (int r = 0; r < 4; ++r) {
                int krel = tile * 16 - 16 + g * 4 + r;
                int dd = li - krel;
                bool ok = ((unsigned)dd < 16u) && (t0 + krel >= 0);
                float v = ok ? st[tile][r] * 0.125f : -1e30f;
                p[tile * 4 + r] = v;
                mx = fmaxf(mx, v);
            }
        }
        mx = fmaxf(mx, __shfl_xor(mx, 16));
        mx = fmaxf(mx, __shfl_xor(mx, 32));
        float sum = 0.f;
        #pragma unroll
        for (int i = 0; i < 8; ++i) { p[i] = __expf(p[i] - mx); sum += p[i]; }
        sum += __shfl_xor(sum, 16);
        sum += __shfl_xor(sum, 32);
        const float inv = 1.0f / sum;

        // P -> wave-local LDS relayout to K=32 A-fragment
        bf16x8 paf;
        {
            char* pbase = p_att + h * 1024;
            uint2 w0, w1;
            w0.x = (unsigned)f2bf(p[0] * inv) | ((unsigned)f2bf(p[1] * inv) << 16);
            w0.y = (unsigned)f2bf(p[2] * inv) | ((unsigned)f2bf(p[3] * inv) << 16);
            w1.x = (unsigned)f2bf(p[4] * inv) | ((unsigned)f2bf(p[5] * inv) << 16);
            w1.y = (unsigned)f2bf(p[6] * inv) | ((unsigned)f2bf(p[7] * inv) << 16);
            const int sw = (li & 3) << 4;
            *(uint2*)(pbase + ((li * 64 + 0 * 32 + g * 8) ^ sw)) = w0;
            *(uint2*)(pbase + ((li * 64 + 1 * 32 + g * 8) ^ sw)) = w1;
            asm volatile("s_waitcnt lgkmcnt(0)" ::: "memory");
            paf = *(const bf16x8*)(pbase + ((li * 64 + g * 16) ^ sw));
        }

        // PV via V^T: single b128 B-frag per ctile
        f32x4 o[4] = {};
        #pragma unroll
        for (int ctile = 0; ctile < 4; ++ctile) {
            bf16x8 vf = *(const bf16x8*)(v_t + (ctile * 16 + li) * 80 + g * 16);
            o[ctile] = __builtin_amdgcn_mfma_f32_16x16x32_bf16(paf, vf, o[ctile], 0, 0, 0);
        }

        // inverse rope on chans 48..63; write O to swizzled LDS
        #pragma unroll
        for (int r = 0; r < 4; ++r) {
            const int row = g * 4 + r;
            const int t = t0 + row;
            float o3 = o[3][r];
            float po = __shfl_xor(o3, 1);
            float2 cs = rtab[t * 8 + (li >> 1)];
            o3 = ((li & 1) == 0) ? (o3 * cs.x + po * cs.y) : (-po * cs.y + o3 * cs.x);
            #pragma unroll
            for (int ctile = 0; ctile < 4; ++ctile) {
                const int col = h * 64 + ctile * 16 + li;
                int byte = row * 512 + col * 2;
                byte ^= (row & 7) << 4;
                float val = (ctile == 3) ? o3 : o[ctile][r];
                *(unsigned short*)(o_lds + byte) = f2bf(val);
            }
        }
        // prefetch gates weights (after attn compute, before barrier)
        #pragma unroll
        for (int ks = 0; ks < 4; ++ks)
            gpre[ks] = *(const bf16x8*)(Wpk2 + (size_t)((gate * 4 + colq) * 4 + ks) * 512 + lane16);
    }
    BAR();

    // ---- phase 3: gates (prefetched W) + prefetch out W -----------------
    bf16x8 opre[2][4];
    {
        const float* bg = gate ? bg1 : bg0;
        f32x4 accp = {};
        #pragma unroll
        for (int ks = 0; ks < 4; ++ks) {
            int byte = li * 512 + (gate * 128 + ks * 32 + g * 8) * 2;
            byte ^= (li & 7) << 4;
            bf16x8 a = *(const bf16x8*)(o_lds + byte);
            accp = __builtin_amdgcn_mfma_f32_16x16x32_bf16(a, gpre[ks], accp, 0, 0, 0);
        }
        // prefetch out-projection weights
        #pragma unroll
        for (int nf = 0; nf < 2; ++nf)
            #pragma unroll
            for (int ks = 0; ks < 4; ++ks)
                opre[nf][ks] = *(const bf16x8*)(Wpk2 + (size_t)((8 + w * 2 + nf) * 4 + ks) * 512 + lane16);
        const int cl = colq * 16 + li;
        const int pcol = gate * 64 + cl;
        const float bb = bg[cl];
        #pragma unroll
        for (int r = 0; r < 4; ++r) {
            const int row = g * 4 + r;
            int byte = row * 256 + pcol * 2;
            byte ^= (row & 7) << 4;
            *(unsigned short*)(p_lds + byte) = f2bf(accp[r] + bb);
        }
    }
    BAR();

    // ---- phase 4: out projection (prefetched W) -------------------------
    {
        f32x4 acco[2] = {};
        #pragma unroll
        for (int ks = 0; ks < 4; ++ks) {
            int byte = li * 256 + (ks * 32 + g * 8) * 2;
            byte ^= (li & 7) << 4;
            bf16x8 a = *(const bf16x8*)(p_lds + byte);
            #pragma unroll
            for (int nf = 0; nf < 2; ++nf)
                acco[nf] = __builtin_amdgcn_mfma_f32_16x16x32_bf16(a, opre[nf][ks], acco[nf], 0, 0, 0);
        }
        #pragma unroll
        for (int nf = 0; nf < 2; ++nf) {
            const int col = w * 32 + nf * 16 + li;
            const float bb = bout[col];
            #pragma unroll
            for (int r = 0; r < 4; ++r) {
                const int row = g * 4 + r;
                out[(size_t)(b * T_SEQ + t0 + row) * DMODEL + col] = acco[nf][r] + bb;
            }
        }
    }
#undef WFRAG
}

extern "C" void kernel_launch(void* const* d_in, const int* in_sizes, int n_in,
                              void* d_out, int out_size, void* d_ws, size_t ws_size,
                              hipStream_t stream) {
    const float* H    = (const float*)d_in[0];
    const float* WQ   = (const float*)d_in[1];
    const float* WK   = (const float*)d_in[2];
    const float* WV   = (const float*)d_in[3];
    const float* wq   = (const float*)d_in[4];
    const float* wk   = (const float*)d_in[5];
    const float* wv   = (const float*)d_in[6];
    const float* Wg0  = (const float*)d_in[7];
    const float* bg0  = (const float*)d_in[8];
    const float* Wg1  = (const float*)d_in[9];
    const float* bg1  = (const float*)d_in[10];
    const float* Wout = (const float*)d_in[11];
    const float* bout = (const float*)d_in[12];
    float* out = (float*)d_out;

    char* ws = (char*)d_ws;
    unsigned short* Wallb = (unsigned short*)ws;          // 294,912 B
    float2* rtab = (float2*)(ws + 294912);                // 131,072 B

    conv_w_kernel<<<136, 256, 0, stream>>>(WQ, WK, WV, Wg0, Wg1, Wout, Wallb, rtab);
    fused_kernel<<<B_SZ * T_SEQ / 16, 512, 0, stream>>>(H, Wallb, wq, wk, wv, rtab,
                                                        bg0, bg1, bout, out);
}

// Round 16
// 20.991 us; speedup vs baseline: 2.8616x; 1.0664x over previous
//
#include <hip/hip_runtime.h>
#include <math.h>

#define T_SEQ 2048
#define DMODEL 256
#define C_HEAD 64
#define NH 4
#define NWIN 16
#define B_SZ 4

typedef __attribute__((ext_vector_type(8))) short bf16x8;
typedef __attribute__((ext_vector_type(8))) unsigned short ushort8;
typedef __attribute__((ext_vector_type(4))) float f32x4;

// barrier WITHOUT vmcnt drain: cross-wave comm is LDS-only, so only
// lgkmcnt(0) is required; in-flight global (weight-prefetch) loads survive.
#define BAR() asm volatile("s_waitcnt lgkmcnt(0)\n\ts_barrier" ::: "memory")

static __device__ __forceinline__ unsigned short f2bf(float f) {
    union { float f; unsigned int u; } v; v.f = f;
    unsigned int r = v.u + 0x7FFFu + ((v.u >> 16) & 1u);
    return (unsigned short)(r >> 16);
}

// ---------------- conv_w: pack weights fragment-major + rope table ------
__global__ __launch_bounds__(256) void conv_w_kernel(
    const float* __restrict__ WQ, const float* __restrict__ WK,
    const float* __restrict__ WV, const float* __restrict__ Wg0,
    const float* __restrict__ Wg1, const float* __restrict__ Wout,
    unsigned short* __restrict__ dst, float2* __restrict__ rtab) {
    const int tid = threadIdx.x;
    if (blockIdx.x >= 72) {
        // theta[k] = 10000^(-k/8) = 10^(-k/2), compile-time constants
        const float th_tab[8] = {1.f, 0.31622776601683794f, 0.1f,
                                 0.03162277660168379f, 0.01f,
                                 0.0031622776601683794f, 0.001f,
                                 0.00031622776601683794f};
        const int idx = (blockIdx.x - 72) * 256 + tid;   // 0..16383
        const int t = idx >> 3, k = idx & 7;
        const float fr = (float)t * th_tab[k];
        rtab[idx] = make_float2(cosf(fr), sinf(fr));
        return;
    }
    const int i = blockIdx.x * 256 + tid;               // 18432 vec8
    const float* s; long off; long doff;
    if (i < 12288) {                                    // K=256 region
        const long e = (long)i * 8;
        const int col = (int)(e >> 8), k = (int)(e & 255);
        if      (col < 256) { s = WQ; off = (long)col * 256 + k; }
        else if (col < 320) { s = WK; off = (long)(col - 256) * 256 + k; }
        else                { s = WV; off = (long)(col - 320) * 256 + k; }
        doff = ((long)(col >> 4) * 8 + (k >> 5)) * 512 + ((k >> 3) & 3) * 128 + (col & 15) * 8;
    } else {                                            // K=128 region
        const long e = (long)(i - 12288) * 8;
        const int col = (int)(e >> 7), k = (int)(e & 127);
        if      (col < 64)  { s = Wg0; off = (long)col * 128 + k; }
        else if (col < 128) { s = Wg1; off = (long)(col - 64) * 128 + k; }
        else                { s = Wout; off = (long)(col - 128) * 128 + k; }
        doff = 98304 + ((long)(col >> 4) * 4 + (k >> 5)) * 512 + ((k >> 3) & 3) * 128 + (col & 15) * 8;
    }
    const float4* s4 = (const float4*)(s + off);
    float4 a = s4[0], b = s4[1];
    ushort8 o;
    o[0] = f2bf(a.x); o[1] = f2bf(a.y); o[2] = f2bf(a.z); o[3] = f2bf(a.w);
    o[4] = f2bf(b.x); o[5] = f2bf(b.y); o[6] = f2bf(b.z); o[7] = f2bf(b.w);
    *(ushort8*)(dst + doff) = o;
}

// ---------------- fused kernel, BM=32, 16 waves, counted barriers -------
// grid = B*(T/32) = 256 blocks, 1024 thr (16 waves/CU, VGPR-capped max).
// QKV: waves 0-7 = Q (head=w>>1, tok-half=w&1); waves 8-13 = K/V 16-row
// slabs; waves 14-15 prefetch gates weights. Weight fragments prefetched
// before every barrier (barriers don't drain vmcnt).
__global__ __launch_bounds__(1024) void fused_kernel(
    const float* __restrict__ H, const unsigned short* __restrict__ Wallb,
    const float* __restrict__ wq, const float* __restrict__ wk,
    const float* __restrict__ wv, const float2* __restrict__ rtab,
    const float* __restrict__ bg0, const float* __restrict__ bg1,
    const float* __restrict__ bout, float* __restrict__ out)
{
    __shared__ __align__(16) char smem[62464];
    char* lds_a = smem;            // [48][512B] H staging (24KB)   [phase A]
    char* o_lds = smem;            // [32][512B] O tile (16KB)      [reuse]
    char* p_lds = smem + 16384;    // [32][256B] p tile (8KB)       [reuse]
    char* q_lds = smem + 24576;    // 4 heads x [32][128B] (16KB)
    char* k_lds = smem + 40960;    // [48][128B] (6KB)
    char* v_t   = smem + 47104;    // V^T [64 ch][112B stride] (7KB)
    char* p_att = smem + 54272;    // 8 Q-waves x 1KB

    const int tid = threadIdx.x;
    const int blk = blockIdx.x;
    const int b  = blk >> 6;
    const int t0 = (blk & 63) << 5;

    const unsigned short* Wpk2 = Wallb + 98304;   // K=128 packed region

    const int w  = tid >> 6;       // wave 0..15
    const int l  = tid & 63;
    const int g  = l >> 4;
    const int li = l & 15;
    const int lane16 = l * 8;      // packed-W per-lane elem offset (16B/lane)

    // qkv geometry
    const int sel  = (w >= 11) ? 1 : 0;            // for waves 8..13
    const int slab = (w >= 11) ? (w - 11) : (w - 8);
    int cb0, rowa;
    if (w < 8)       { cb0 = (w >> 1) * 4; rowa = 16 + (w & 1) * 16 + li; }
    else if (w < 14) { cb0 = 16 + sel * 4; rowa = slab * 16 + li; }
    else             { cb0 = 0;            rowa = li; }

#define WFRAG(nf, ks) (*(const bf16x8*)(Wallb + (size_t)((cb0 + (nf)) * 8 + (ks)) * 512 + lane16))

    const int gate = (w >> 3) & 1, colq = (w >> 1) & 3, rh = w & 1;
    bf16x8 gpre[4];

    // ---- phase 0: stage H rows [t0-16, t0+32) + prefetch qkv W ----------
    for (int idx = tid; idx < 1536; idx += 1024) {
        int row = idx >> 5, ch = idx & 31;
        int t = t0 - 16 + row; if (t < 0) t = 0;       // masked later
        const float4* s4 = (const float4*)(H + ((size_t)b * T_SEQ + t) * DMODEL + ch * 8);
        float4 a = s4[0], c = s4[1];
        ushort8 o;
        o[0] = f2bf(a.x); o[1] = f2bf(a.y); o[2] = f2bf(a.z); o[3] = f2bf(a.w);
        o[4] = f2bf(c.x); o[5] = f2bf(c.y); o[6] = f2bf(c.z); o[7] = f2bf(c.w);
        int byte = row * 512 + ch * 16;
        byte ^= (row & 7) << 4;
        *(ushort8*)(lds_a + byte) = o;
    }
    bf16x8 cur[4], nxt[4];
    if (w < 14) {
        #pragma unroll
        for (int nf = 0; nf < 4; ++nf) { cur[nf] = WFRAG(nf, 0); nxt[nf] = WFRAG(nf, 1); }
    } else {
        // idle waves: prefetch their gates weights now
        #pragma unroll
        for (int ks = 0; ks < 4; ++ks)
            gpre[ks] = *(const bf16x8*)(Wpk2 + (size_t)((gate * 4 + colq) * 4 + ks) * 512 + lane16);
    }
    BAR();

    // ---- phase 1: qkv with 2-deep rolling weight prefetch ---------------
    if (w < 14) {
        f32x4 acc[4] = {};
        #pragma unroll
        for (int ks = 0; ks < 8; ++ks) {
            bf16x8 fut[4];
            if (ks < 6) {
                #pragma unroll
                for (int nf = 0; nf < 4; ++nf) fut[nf] = WFRAG(nf, ks + 2);
            }
            int abyte = rowa * 512 + (ks * 32 + g * 8) * 2;
            abyte ^= (rowa & 7) << 4;
            bf16x8 a = *(const bf16x8*)(lds_a + abyte);
            #pragma unroll
            for (int nf = 0; nf < 4; ++nf)
                acc[nf] = __builtin_amdgcn_mfma_f32_16x16x32_bf16(a, cur[nf], acc[nf], 0, 0, 0);
            #pragma unroll
            for (int nf = 0; nf < 4; ++nf) { cur[nf] = nxt[nf]; nxt[nf] = fut[nf]; }
        }

        if (w < 8) {
            const int h = w >> 1;
            float gw[4];
            #pragma unroll
            for (int nf = 0; nf < 4; ++nf) gw[nf] = wq[h * 64 + nf * 16 + li];
            #pragma unroll
            for (int r = 0; r < 4; ++r) {
                float x0 = acc[0][r], x1 = acc[1][r];
                float x2 = acc[2][r], x3 = acc[3][r];
                float ss = x0 * x0 + x1 * x1 + x2 * x2 + x3 * x3;
                ss += __shfl_xor(ss, 1);
                ss += __shfl_xor(ss, 2);
                ss += __shfl_xor(ss, 4);
                ss += __shfl_xor(ss, 8);
                const float rinv = rsqrtf(ss * (1.0f / 64.0f) + 1e-8f);
                const int tok = (w & 1) * 16 + g * 4 + r;   // 0..31
                const int t = t0 + tok;
                float v0 = x0 * rinv * gw[0];
                float v1 = x1 * rinv * gw[1];
                float v2 = x2 * rinv * gw[2];
                float v3 = x3 * rinv * gw[3];
                float2 cs = rtab[t * 8 + (li >> 1)];
                float px = __shfl_xor(v3, 1);
                v3 = ((li & 1) == 0) ? (v3 * cs.x - px * cs.y) : (px * cs.y + v3 * cs.x);
                char* qb = q_lds + h * 4096;
                const int sw = (tok & 7) << 4;
                *(unsigned short*)(qb + ((tok * 128 + (0 * 16 + li) * 2) ^ sw)) = f2bf(v0);
                *(unsigned short*)(qb + ((tok * 128 + (1 * 16 + li) * 2) ^ sw)) = f2bf(v1);
                *(unsigned short*)(qb + ((tok * 128 + (2 * 16 + li) * 2) ^ sw)) = f2bf(v2);
                *(unsigned short*)(qb + ((tok * 128 + (3 * 16 + li) * 2) ^ sw)) = f2bf(v3);
            }
        } else {
            float gw[4];
            #pragma unroll
            for (int nf = 0; nf < 4; ++nf)
                gw[nf] = (sel == 0) ? wk[nf * 16 + li] : wv[nf * 16 + li];
            #pragma unroll
            for (int r = 0; r < 4; ++r) {
                float x0 = acc[0][r], x1 = acc[1][r];
                float x2 = acc[2][r], x3 = acc[3][r];
                float ss = x0 * x0 + x1 * x1 + x2 * x2 + x3 * x3;
                ss += __shfl_xor(ss, 1);
                ss += __shfl_xor(ss, 2);
                ss += __shfl_xor(ss, 4);
                ss += __shfl_xor(ss, 8);
                const float rinv = rsqrtf(ss * (1.0f / 64.0f) + 1e-8f);
                const int row = slab * 16 + g * 4 + r;     // halo row 0..47
                int tk = t0 - 16 + row; if (tk < 0) tk = 0;
                float v0 = x0 * rinv * gw[0];
                float v1 = x1 * rinv * gw[1];
                float v2 = x2 * rinv * gw[2];
                float v3 = x3 * rinv * gw[3];
                float2 cs = rtab[tk * 8 + (li >> 1)];
                float px = __shfl_xor(v3, 1);
                v3 = ((li & 1) == 0) ? (v3 * cs.x - px * cs.y) : (px * cs.y + v3 * cs.x);
                if (sel == 0) {
                    const int sw = (row & 7) << 4;
                    *(unsigned short*)(k_lds + ((row * 128 + (0 * 16 + li) * 2) ^ sw)) = f2bf(v0);
                    *(unsigned short*)(k_lds + ((row * 128 + (1 * 16 + li) * 2) ^ sw)) = f2bf(v1);
                    *(unsigned short*)(k_lds + ((row * 128 + (2 * 16 + li) * 2) ^ sw)) = f2bf(v2);
                    *(unsigned short*)(k_lds + ((row * 128 + (3 * 16 + li) * 2) ^ sw)) = f2bf(v3);
                } else {
                    *(unsigned short*)(v_t + (0 * 16 + li) * 112 + row * 2) = f2bf(v0);
                    *(unsigned short*)(v_t + (1 * 16 + li) * 112 + row * 2) = f2bf(v1);
                    *(unsigned short*)(v_t + (2 * 16 + li) * 112 + row * 2) = f2bf(v2);
                    *(unsigned short*)(v_t + (3 * 16 + li) * 112 + row * 2) = f2bf(v3);
                }
            }
        }
    }
    BAR();

    // ---- phase 2: attention (waves 0-7); waves 8-13 prefetch gates W ----
    if (w >= 8 && w < 14) {
        #pragma unroll
        for (int ks = 0; ks < 4; ++ks)
            gpre[ks] = *(const bf16x8*)(Wpk2 + (size_t)((gate * 4 + colq) * 4 + ks) * 512 + lane16);
    }
    if (w < 8) {
        const int h  = w >> 1;
        const int th = w & 1;
        bf16x8 qf0, qf1;
        {
            const char* qb = q_lds + h * 4096;
            const int tok = th * 16 + li;
            const int sw = (tok & 7) << 4;
            qf0 = *(const bf16x8*)(qb + ((tok * 128 + g * 16) ^ sw));
            qf1 = *(const bf16x8*)(qb + ((tok * 128 + 64 + g * 16) ^ sw));
        }
        f32x4 st[2];
        #pragma unroll
        for (int tile = 0; tile < 2; ++tile) {
            const int row = th * 16 + tile * 16 + li;  // halo key row
            const int sw = (row & 7) << 4;
            bf16x8 kf0 = *(const bf16x8*)(k_lds + ((row * 128 + g * 16) ^ sw));
            bf16x8 kf1 = *(const bf16x8*)(k_lds + ((row * 128 + 64 + g * 16) ^ sw));
            f32x4 sa = {};
            sa = __builtin_amdgcn_mfma_f32_16x16x32_bf16(kf0, qf0, sa, 0, 0, 0);
            sa = __builtin_amdgcn_mfma_f32_16x16x32_bf16(kf1, qf1, sa, 0, 0, 0);
            st[tile] = sa;
        }

        float p[8];
        float mx = -1e30f;
        #pragma unroll
        for (int tile = 0; tile < 2; ++tile) {
            #pragma unroll
            for (int r = 0; r < 4; ++r) {
                int krel = tile * 16 - 16 + g * 4 + r;    // key - token_base
                int dd = li - krel;                        // token - key
                bool ok = ((unsigned)dd < 16u) && (t0 + th * 16 + krel >= 0);
                float v = ok ? st[tile][r] * 0.125f : -1e30f;
                p[tile * 4 + r] = v;
                mx = fmaxf(mx, v);
            }
        }
        mx = fmaxf(mx, __shfl_xor(mx, 16));
        mx = fmaxf(mx, __shfl_xor(mx, 32));
        float sum = 0.f;
        #pragma unroll
        for (int i = 0; i < 8; ++i) { p[i] = __expf(p[i] - mx); sum += p[i]; }
        sum += __shfl_xor(sum, 16);
        sum += __shfl_xor(sum, 32);
        const float inv = 1.0f / sum;

        // P -> wave-local LDS relayout to K=32 A-fragment
        bf16x8 paf;
        {
            char* pbase = p_att + w * 1024;
            uint2 w0, w1;
            w0.x = (unsigned)f2bf(p[0] * inv) | ((unsigned)f2bf(p[1] * inv) << 16);
            w0.y = (unsigned)f2bf(p[2] * inv) | ((unsigned)f2bf(p[3] * inv) << 16);
            w1.x = (unsigned)f2bf(p[4] * inv) | ((unsigned)f2bf(p[5] * inv) << 16);
            w1.y = (unsigned)f2bf(p[6] * inv) | ((unsigned)f2bf(p[7] * inv) << 16);
            const int sw = (li & 3) << 4;
            *(uint2*)(pbase + ((li * 64 + 0 * 32 + g * 8) ^ sw)) = w0;
            *(uint2*)(pbase + ((li * 64 + 1 * 32 + g * 8) ^ sw)) = w1;
            asm volatile("s_waitcnt lgkmcnt(0)" ::: "memory");
            paf = *(const bf16x8*)(pbase + ((li * 64 + g * 16) ^ sw));
        }

        // PV via V^T: single b128 B-frag per ctile
        f32x4 o[4] = {};
        #pragma unroll
        for (int ctile = 0; ctile < 4; ++ctile) {
            bf16x8 vf = *(const bf16x8*)(v_t + (ctile * 16 + li) * 112 + th * 32 + g * 16);
            o[ctile] = __builtin_amdgcn_mfma_f32_16x16x32_bf16(paf, vf, o[ctile], 0, 0, 0);
        }

        // inverse rope on chans 48..63; write O to swizzled LDS
        #pragma unroll
        for (int r = 0; r < 4; ++r) {
            const int row = th * 16 + g * 4 + r;       // 0..31
            const int t = t0 + row;
            float o3 = o[3][r];
            float po = __shfl_xor(o3, 1);
            float2 cs = rtab[t * 8 + (li >> 1)];
            o3 = ((li & 1) == 0) ? (o3 * cs.x + po * cs.y) : (-po * cs.y + o3 * cs.x);
            #pragma unroll
            for (int ctile = 0; ctile < 4; ++ctile) {
                const int col = h * 64 + ctile * 16 + li;
                int byte = row * 512 + col * 2;
                byte ^= (row & 7) << 4;
                float val = (ctile == 3) ? o3 : o[ctile][r];
                *(unsigned short*)(o_lds + byte) = f2bf(val);
            }
        }
        // prefetch gates weights (after attn compute, before barrier)
        #pragma unroll
        for (int ks = 0; ks < 4; ++ks)
            gpre[ks] = *(const bf16x8*)(Wpk2 + (size_t)((gate * 4 + colq) * 4 + ks) * 512 + lane16);
    }
    BAR();

    // ---- phase 3: gates (prefetched W) + prefetch out W -----------------
    bf16x8 opre[4];
    {
        const float* bg = gate ? bg1 : bg0;
        f32x4 accp = {};
        #pragma unroll
        for (int ks = 0; ks < 4; ++ks) {
            const int row = rh * 16 + li;
            int byte = row * 512 + (gate * 128 + ks * 32 + g * 8) * 2;
            byte ^= (row & 7) << 4;
            bf16x8 a = *(const bf16x8*)(o_lds + byte);
            accp = __builtin_amdgcn_mfma_f32_16x16x32_bf16(a, gpre[ks], accp, 0, 0, 0);
        }
        // prefetch out-projection weights (colblk = 8 + w)
        #pragma unroll
        for (int ks = 0; ks < 4; ++ks)
            opre[ks] = *(const bf16x8*)(Wpk2 + (size_t)((8 + w) * 4 + ks) * 512 + lane16);
        const int cl = colq * 16 + li;
        const int pcol = gate * 64 + cl;
        const float bb = bg[cl];
        #pragma unroll
        for (int r = 0; r < 4; ++r) {
            const int row = rh * 16 + g * 4 + r;
            int byte = row * 256 + pcol * 2;
            byte ^= (row & 7) << 4;
            *(unsigned short*)(p_lds + byte) = f2bf(accp[r] + bb);
        }
    }
    BAR();

    // ---- phase 4: out. wave w -> cols w*16 .. w*16+15, 32 rows ----------
    {
        f32x4 acco[2] = {};
        #pragma unroll
        for (int ks = 0; ks < 4; ++ks) {
            bf16x8 a[2];
            #pragma unroll
            for (int mf = 0; mf < 2; ++mf) {
                const int row = mf * 16 + li;
                int byte = row * 256 + (ks * 32 + g * 8) * 2;
                byte ^= (row & 7) << 4;
                a[mf] = *(const bf16x8*)(p_lds + byte);
            }
            acco[0] = __builtin_amdgcn_mfma_f32_16x16x32_bf16(a[0], opre[ks], acco[0], 0, 0, 0);
            acco[1] = __builtin_amdgcn_mfma_f32_16x16x32_bf16(a[1], opre[ks], acco[1], 0, 0, 0);
        }
        const int col = w * 16 + li;
        const float bb = bout[col];
        #pragma unroll
        for (int mf = 0; mf < 2; ++mf) {
            #pragma unroll
            for (int r = 0; r < 4; ++r) {
                const int row = mf * 16 + g * 4 + r;
                out[(size_t)(b * T_SEQ + t0 + row) * DMODEL + col] = acco[mf][r] + bb;
            }
        }
    }
#undef WFRAG
}

extern "C" void kernel_launch(void* const* d_in, const int* in_sizes, int n_in,
                              void* d_out, int out_size, void* d_ws, size_t ws_size,
                              hipStream_t stream) {
    const float* H    = (const float*)d_in[0];
    const float* WQ   = (const float*)d_in[1];
    const float* WK   = (const float*)d_in[2];
    const float* WV   = (const float*)d_in[3];
    const float* wq   = (const float*)d_in[4];
    const float* wk   = (const float*)d_in[5];
    const float* wv   = (const float*)d_in[6];
    const float* Wg0  = (const float*)d_in[7];
    const float* bg0  = (const float*)d_in[8];
    const float* Wg1  = (const float*)d_in[9];
    const float* bg1  = (const float*)d_in[10];
    const float* Wout = (const float*)d_in[11];
    const float* bout = (const float*)d_in[12];
    float* out = (float*)d_out;

    char* ws = (char*)d_ws;
    unsigned short* Wallb = (unsigned short*)ws;          // 294,912 B
    float2* rtab = (float2*)(ws + 294912);                // 131,072 B

    conv_w_kernel<<<136, 256, 0, stream>>>(WQ, WK, WV, Wg0, Wg1, Wout, Wallb, rtab);
    fused_kernel<<<B_SZ * T_SEQ / 32, 1024, 0, stream>>>(H, Wallb, wq, wk, wv, rtab,
                                                         bg0, bg1, bout, out);
}